// Round 14
// baseline (295.067 us; speedup 1.0000x reference)
//
#include <hip/hip_runtime.h>

constexpr int kB   = 8;
constexpr int kN   = 64;
constexpr int kE   = 192;
constexpr int kDin = 1024;
constexpr int kDp  = 256;
constexpr int kNN  = 4096;
constexpr float kTauInv = 20.0f;
constexpr int kXS  = 16;     // x row stride (ss channel lives in LDS only)

typedef float vfloat4 __attribute__((ext_vector_type(4)));

// ===========================================================================
// K1: projection GEMM 64x64 tiles, z=2 split-K (blocks 0..511)
//     + CSR build (blocks 512..519).  CSR block b==0 also zeroes stats.
// ===========================================================================
struct SmemGemm { float As[2][16][68]; float Ws[2][16][68]; };
struct SmemCsr  {
    int km1[4096], km2[4096];
    short es1[kE], es2[kE], rp1[kE], rp2[kE];
    int cnt1[64], cnt2[64], pos1[64], pos2[64];
    int ccnt1[kE], ccnt2[kE], cpos1[kE], cpos2[kE];
};
union __align__(16) SmemK1 { SmemGemm g; SmemCsr csr; };

__global__ __launch_bounds__(256) void k_projcsr(
    const float* __restrict__ x1, const float* __restrict__ x2,
    const float* __restrict__ e1, const float* __restrict__ e2,
    const float* __restrict__ Wp,
    const int* __restrict__ src1, const int* __restrict__ dst1,
    const int* __restrict__ src2, const int* __restrict__ dst2,
    float* __restrict__ P, float* __restrict__ stats,
    int* __restrict__ off1, int* __restrict__ off2,
    int* __restrict__ lst1, int* __restrict__ lst2,
    int* __restrict__ rep1g, int* __restrict__ rep2g,
    int* __restrict__ coff1, int* __restrict__ coff2,
    int* __restrict__ clst1, int* __restrict__ clst2)
{
    const int bid = blockIdx.x, t = threadIdx.x;
    __shared__ SmemK1 u;

    if (bid < 512) {
        const int z = bid >> 8;                 // 0..1 K-half
        const int rt = (bid >> 2) & 63, ct = bid & 3;
        const int grow0 = rt * 64, col0 = ct * 64;
        const float* src; int lrow0;
        if (rt < 8)       { src = x1; lrow0 = grow0; }
        else if (rt < 16) { src = x2; lrow0 = grow0 - 512; }
        else if (rt < 40) { src = e1; lrow0 = grow0 - 1024; }
        else              { src = e2; lrow0 = grow0 - 2560; }

        const int tx = t & 15, ty = t >> 4;
        const int arow = t >> 2, acol = (t & 3) * 4;
        const int wrow = t >> 4, wcol = (t & 15) * 4;

        const float* Abase = src + (size_t)(lrow0 + arow) * kDin + z * 512 + acol;
        const float* Wbase = Wp + (size_t)(z * 512 + wrow) * kDp + col0 + wcol;

        float4 a4 = *(const float4*)Abase;
        float4 w4 = *(const float4*)Wbase;
        float acc[4][4] = {};

        for (int c = 0; c < 32; ++c) {
            const int cur = c & 1;
            u.g.As[cur][acol + 0][arow] = a4.x;
            u.g.As[cur][acol + 1][arow] = a4.y;
            u.g.As[cur][acol + 2][arow] = a4.z;
            u.g.As[cur][acol + 3][arow] = a4.w;
            *(float4*)&u.g.Ws[cur][wrow][wcol] = w4;
            __syncthreads();
            if (c < 31) {
                a4 = *(const float4*)(Abase + (c + 1) * 16);
                w4 = *(const float4*)(Wbase + (size_t)(c + 1) * 16 * kDp);
            }
#pragma unroll
            for (int kk = 0; kk < 16; ++kk) {
                float4 av = *(const float4*)&u.g.As[cur][kk][ty * 4];
                float4 wv = *(const float4*)&u.g.Ws[cur][kk][tx * 4];
                float a[4] = {av.x, av.y, av.z, av.w};
                float w[4] = {wv.x, wv.y, wv.z, wv.w};
#pragma unroll
                for (int i = 0; i < 4; ++i)
#pragma unroll
                    for (int j = 0; j < 4; ++j)
                        acc[i][j] += a[i] * w[j];
            }
        }
        float* Pz = P + (size_t)z * 1048576;
#pragma unroll
        for (int i = 0; i < 4; ++i) {
            const int row = grow0 + ty * 4 + i;
            float4 v;
            v.x = acc[i][0]; v.y = acc[i][1]; v.z = acc[i][2]; v.w = acc[i][3];
            *(float4*)&Pz[(size_t)row * kDp + col0 + tx * 4] = v;
        }
    } else {
        const int b = bid - 512;
        auto& C = u.csr;
        if (b == 0)
            for (int i = t; i < 2048; i += 256) stats[i] = 0.f;
        for (int i = t; i < 4096; i += 256) {
            C.km1[i] = 0x7fffffff; C.km2[i] = 0x7fffffff;
        }
        if (t < 64) { C.cnt1[t] = 0; C.cnt2[t] = 0; }
        for (int i = t; i < kE; i += 256) { C.ccnt1[i] = 0; C.ccnt2[i] = 0; }
        __syncthreads();
        if (t < kE) {
            int v1 = src1[b * kE + t], v2 = src2[b * kE + t];
            C.es1[t] = (short)v1; C.es2[t] = (short)v2;
            atomicAdd(&C.cnt1[v1], 1);
            atomicAdd(&C.cnt2[v2], 1);
            atomicMin(&C.km1[v1 * 64 + dst1[b * kE + t]], t);
            atomicMin(&C.km2[v2 * 64 + dst2[b * kE + t]], t);
        }
        __syncthreads();
        if (t < kE) {
            int r1 = C.km1[C.es1[t] * 64 + dst1[b * kE + t]];
            int r2 = C.km2[C.es2[t] * 64 + dst2[b * kE + t]];
            C.rp1[t] = (short)r1; C.rp2[t] = (short)r2;
            rep1g[b * kE + t] = r1; rep2g[b * kE + t] = r2;
            atomicAdd(&C.ccnt1[r1], 1);
            atomicAdd(&C.ccnt2[r2], 1);
        }
        __syncthreads();
        if (t == 0) {
            int a = 0, c = 0;
            for (int v = 0; v < 64; ++v) { C.pos1[v] = a; a += C.cnt1[v]; C.pos2[v] = c; c += C.cnt2[v]; }
            a = 0; c = 0;
            for (int v = 0; v < kE; ++v) { C.cpos1[v] = a; a += C.ccnt1[v]; C.cpos2[v] = c; c += C.ccnt2[v]; }
        }
        __syncthreads();
        if (t < 64) { off1[b * 65 + t] = C.pos1[t]; off2[b * 65 + t] = C.pos2[t]; }
        if (t == 0) { off1[b * 65 + 64] = kE; off2[b * 65 + 64] = kE; }
        if (t < kE) { coff1[b * 193 + t] = C.cpos1[t]; coff2[b * 193 + t] = C.cpos2[t]; }
        if (t == 0) { coff1[b * 193 + kE] = kE; coff2[b * 193 + kE] = kE; }
        __syncthreads();
        if (t < kE) {
            int p = atomicAdd(&C.pos1[C.es1[t]], 1); lst1[b * kE + p] = t;
            int q = atomicAdd(&C.pos2[C.es2[t]], 1); lst2[b * kE + q] = t;
            int cp = atomicAdd(&C.cpos1[C.rp1[t]], 1); clst1[b * kE + cp] = t;
            int cq = atomicAdd(&C.cpos2[C.rp2[t]], 1); clst2[b * kE + cq] = t;
        }
    }
}

// ===========================================================================
// K1b: reduce split-K partials + bias -> hbuf, accumulate BN stats.
// ===========================================================================
__global__ __launch_bounds__(256) void k_reduce(
    const float* __restrict__ P, const float* __restrict__ bp,
    float* __restrict__ hbuf, float* __restrict__ stats)
{
    const int t = threadIdx.x;
    const int r0 = blockIdx.x * 16;
    const int seg = (r0 < 512) ? 0 : (r0 < 1024 ? 1 : (r0 < 2560 ? 2 : 3));
    const float bb = bp[t];
    float s = 0.f, s2 = 0.f;
#pragma unroll
    for (int rr = 0; rr < 16; ++rr) {
        size_t o = (size_t)(r0 + rr) * kDp + t;
        float v = P[o] + P[o + 1048576] + bb;
        hbuf[o] = v;
        s += v; s2 += v * v;
    }
    atomicAdd(&stats[seg * 512 + t], s);
    atomicAdd(&stats[seg * 512 + 256 + t], s2);
}

// ===========================================================================
// K2: similarity GEMMs with inline BN+ReLU+L2.  320 blocks.
// Block 0 zeroes the 2 barrier words used by k_final.
// ===========================================================================
struct __align__(16) SmemSim  {
    float Xs[32][36]; float Ys[32][36];
    float muX[256], isX[256], muY[256], isY[256];
    float ga[256], be[256];
    float scX[32], scY[32];
};

__global__ __launch_bounds__(256) void k_sim(
    const float* __restrict__ hbuf, const float* __restrict__ stats,
    const float* __restrict__ gamma, const float* __restrict__ beta,
    float* __restrict__ Kp, float* __restrict__ Ke,
    int* __restrict__ bars)
{
    const int bid = blockIdx.x, t = threadIdx.x;
    __shared__ SmemSim u;

    if (bid == 0 && t == 0) { bars[3584] = 0; bars[3600] = 0; }

    const int id = bid % 40, b = bid / 40;
    int mt, nt_, ldo, segX, segY, xrow0, yrow0; float* outp; float scale;
    if (id < 4) {
        mt = (id >> 1) * 32; nt_ = (id & 1) * 32; ldo = 64;
        xrow0 = b * 64; yrow0 = 512 + b * 64;
        segX = 0; segY = 1;
        outp = Kp + (size_t)b * 4096; scale = 1.0f;
    } else {
        int e = id - 4;
        mt = (e / 6) * 32; nt_ = (e % 6) * 32; ldo = 192;
        xrow0 = 1024 + b * 192; yrow0 = 2560 + b * 192;
        segX = 2; segY = 3;
        outp = Ke + (size_t)b * 36864; scale = 0.5f;
    }
    {
        const float n = (segX < 2) ? 512.f : 1536.f;
        float mu = stats[segX * 512 + t] / n;
        float var = stats[segX * 512 + 256 + t] / n - mu * mu;
        u.muX[t] = mu; u.isX[t] = rsqrtf(var + 1e-5f);
        mu = stats[segY * 512 + t] / n;
        var = stats[segY * 512 + 256 + t] / n - mu * mu;
        u.muY[t] = mu; u.isY[t] = rsqrtf(var + 1e-5f);
        u.ga[t] = gamma[t]; u.be[t] = beta[t];
    }
    __syncthreads();
    {
        const int ri = t >> 2, lane = t & 3;
        const bool isXr = ri < 32;
        const int grow = isXr ? (xrow0 + mt + ri) : (yrow0 + nt_ + (ri - 32));
        const float* mus = isXr ? u.muX : u.muY;
        const float* iss = isXr ? u.isX : u.isY;
        const float* hr = hbuf + (size_t)grow * kDp;
        float ss = 0.f;
        for (int c4 = 0; c4 < 16; ++c4) {
            int c = lane * 64 + c4 * 4;
            float4 v = *(const float4*)&hr[c];
            float p;
            p = fmaxf((v.x - mus[c+0]) * iss[c+0] * u.ga[c+0] + u.be[c+0], 0.f); ss += p * p;
            p = fmaxf((v.y - mus[c+1]) * iss[c+1] * u.ga[c+1] + u.be[c+1], 0.f); ss += p * p;
            p = fmaxf((v.z - mus[c+2]) * iss[c+2] * u.ga[c+2] + u.be[c+2], 0.f); ss += p * p;
            p = fmaxf((v.w - mus[c+3]) * iss[c+3] * u.ga[c+3] + u.be[c+3], 0.f); ss += p * p;
        }
        ss += __shfl_xor(ss, 1);
        ss += __shfl_xor(ss, 2);
        if (lane == 0) {
            float sc = 1.f / fmaxf(sqrtf(ss), 1e-12f);
            if (isXr) u.scX[ri] = sc; else u.scY[ri - 32] = sc;
        }
    }
    __syncthreads();
    const int row = t >> 3, kq = t & 7;
    const int ty = t >> 4, tx = t & 15;
    const float* Xp = hbuf + (size_t)(xrow0 + mt) * kDp;
    const float* Yp = hbuf + (size_t)(yrow0 + nt_) * kDp;
    float acc[2][2] = {};
    for (int k0 = 0; k0 < kDp; k0 += 32) {
        const int c = k0 + kq * 4;
        float4 xa = *(const float4*)(Xp + (size_t)row * kDp + c);
        float4 ya = *(const float4*)(Yp + (size_t)row * kDp + c);
        const float sx = u.scX[row], sy = u.scY[row];
        u.Xs[kq*4+0][row] = fmaxf((xa.x - u.muX[c+0]) * u.isX[c+0] * u.ga[c+0] + u.be[c+0], 0.f) * sx;
        u.Xs[kq*4+1][row] = fmaxf((xa.y - u.muX[c+1]) * u.isX[c+1] * u.ga[c+1] + u.be[c+1], 0.f) * sx;
        u.Xs[kq*4+2][row] = fmaxf((xa.z - u.muX[c+2]) * u.isX[c+2] * u.ga[c+2] + u.be[c+2], 0.f) * sx;
        u.Xs[kq*4+3][row] = fmaxf((xa.w - u.muX[c+3]) * u.isX[c+3] * u.ga[c+3] + u.be[c+3], 0.f) * sx;
        u.Ys[kq*4+0][row] = fmaxf((ya.x - u.muY[c+0]) * u.isY[c+0] * u.ga[c+0] + u.be[c+0], 0.f) * sy;
        u.Ys[kq*4+1][row] = fmaxf((ya.y - u.muY[c+1]) * u.isY[c+1] * u.ga[c+1] + u.be[c+1], 0.f) * sy;
        u.Ys[kq*4+2][row] = fmaxf((ya.z - u.muY[c+2]) * u.isY[c+2] * u.ga[c+2] + u.be[c+2], 0.f) * sy;
        u.Ys[kq*4+3][row] = fmaxf((ya.w - u.muY[c+3]) * u.isY[c+3] * u.ga[c+3] + u.be[c+3], 0.f) * sy;
        __syncthreads();
#pragma unroll
        for (int kk = 0; kk < 32; ++kk) {
            float2 xv = *(const float2*)&u.Xs[kk][ty * 2];
            float2 yv = *(const float2*)&u.Ys[kk][tx * 2];
            acc[0][0] += xv.x * yv.x; acc[0][1] += xv.x * yv.y;
            acc[1][0] += xv.y * yv.x; acc[1][1] += xv.y * yv.y;
        }
        __syncthreads();
    }
#pragma unroll
    for (int i = 0; i < 2; ++i)
#pragma unroll
        for (int j = 0; j < 2; ++j)
            outp[(size_t)(mt + ty * 2 + i) * ldo + nt_ + tx * 2 + j] = scale * acc[i][j];
}

// ===========================================================================
// K3a/b/c: one GNN layer per kernel (512 blocks each).
// R13 lesson: LDS staging of 64-row x-groups serialized the block on
// {barrier, 4KB fetch, barrier} per edge-group (7x overfetch, 45us,
// occupancy 12.8%).  Now: each 4-lane group loads the exact x row it
// needs as one float4/lane, directly from cache — no staging barriers,
// loads across edge pairs stay in flight.  Per-channel FP order unchanged.
// ===========================================================================
struct __align__(16) SmemLayer {
    float mat[64][68]; float fL[64], gL[64];
    float WL[17 * 16]; float bL[16], SL[16]; float c0v;
    float WcL[17];
    int jd2[kE]; int il[kE]; float msgT[64][18];
    int co1L[kE + 1], co2L[kE + 1];
    short cl1L[kE], cl2L[kE];
};

// Local per-block 64x64 sinkhorn (4-lane rows, static unrolls).
__device__ void sink64_local(int b, int t, float (*mat)[68], float* fL, float* gL,
                             const float* __restrict__ vin)
{
    const float4* v4 = (const float4*)(vin + b * kNN);
    for (int i = t; i < 1024; i += 256) {
        float4 v = v4[i];
        int idx = i * 4;
        int q = idx >> 6, p = idx & 63;
        mat[p][q]     = v.x * kTauInv;
        mat[p + 1][q] = v.y * kTauInv;
        mat[p + 2][q] = v.z * kTauInv;
        mat[p + 3][q] = v.w * kTauInv;
    }
    if (t < 64) { fL[t] = 0.f; gL[t] = 0.f; }
    __syncthreads();
    const int r = t >> 2, s = t & 3;
    float tv[16];
    for (int it = 0; it < 10; ++it) {
        float mx = -1e30f;
#pragma unroll
        for (int k = 0; k < 16; ++k) {
            float v = mat[r][s + 4 * k] + gL[s + 4 * k];
            tv[k] = v; mx = fmaxf(mx, v);
        }
        mx = fmaxf(mx, __shfl_xor(mx, 1));
        mx = fmaxf(mx, __shfl_xor(mx, 2));
        float sum = 0.f;
#pragma unroll
        for (int k = 0; k < 16; ++k) sum += __expf(tv[k] - mx);
        sum += __shfl_xor(sum, 1);
        sum += __shfl_xor(sum, 2);
        if (s == 0) fL[r] = -(mx + __logf(sum));
        __syncthreads();
        mx = -1e30f;
#pragma unroll
        for (int k = 0; k < 16; ++k) {
            float v = mat[s + 4 * k][r] + fL[s + 4 * k];
            tv[k] = v; mx = fmaxf(mx, v);
        }
        mx = fmaxf(mx, __shfl_xor(mx, 1));
        mx = fmaxf(mx, __shfl_xor(mx, 2));
        sum = 0.f;
#pragma unroll
        for (int k = 0; k < 16; ++k) sum += __expf(tv[k] - mx);
        sum += __shfl_xor(sum, 1);
        sum += __shfl_xor(sum, 2);
        if (s == 0) gL[r] = -(mx + __logf(sum));
        __syncthreads();
    }
    const float fr = fL[r];
#pragma unroll
    for (int k = 0; k < 16; ++k) {
        int q = s + 4 * k;
        mat[r][q] = __expf(mat[r][q] + fr + gL[q]);
    }
    __syncthreads();
}

template <int C, bool LASTP>
__device__ void layer_body(int bid, int t, SmemLayer& L,
    const int* __restrict__ off1, const int* __restrict__ lst1,
    const int* __restrict__ off2, const int* __restrict__ lst2,
    const int* __restrict__ d1, const int* __restrict__ d2,
    const int* __restrict__ rep1g, const int* __restrict__ rep2g,
    const int* __restrict__ coff1, const int* __restrict__ coff2,
    const int* __restrict__ clst1, const int* __restrict__ clst2,
    const float* __restrict__ Ke, const float* __restrict__ x,
    const float* __restrict__ Kp, int* __restrict__ degcnt,
    const float* __restrict__ W, const float* __restrict__ bb,
    const float* __restrict__ S, const float* __restrict__ c0,
    const float* __restrict__ Wc,
    const float* __restrict__ vprev, float* __restrict__ xn,
    float* __restrict__ vcbuf, float* __restrict__ vout)
{
    const int r2 = bid & 63, b = bid >> 6;
    for (int k = t; k < C * 16; k += 256) L.WL[k] = W[k];
    if (t < 16) { L.bL[t] = bb[t]; L.SL[t] = S[t]; }
    if (t == 0) L.c0v = c0[0];
    if (LASTP && t < 17) L.WcL[t] = Wc[t];
    const int j0 = off2[b * 65 + r2];
    const int n2 = off2[b * 65 + r2 + 1] - j0;
    for (int k = t; k < n2; k += 256) {
        int j = lst2[b * kE + j0 + k];
        int v = (j << 8) | d2[b * kE + j];
        if (C == 1 && rep2g[b * kE + j] == j) v |= 1 << 16;
        L.jd2[k] = v;
    }
    for (int k = t; k < kE; k += 256) {
        int i = lst1[b * kE + k];
        int v = (i << 8) | d1[b * kE + i];
        if (C == 1 && rep1g[b * kE + i] == i) v |= 1 << 16;
        L.il[k] = v;
    }
    if constexpr (C == 1) {
        for (int k = t; k < kE + 1; k += 256) {
            L.co1L[k] = coff1[b * 193 + k];
            L.co2L[k] = coff2[b * 193 + k];
        }
        for (int k = t; k < kE; k += 256) {
            L.cl1L[k] = (short)clst1[b * kE + k];
            L.cl2L[k] = (short)clst2[b * kE + k];
        }
    }
    if constexpr (C == 17) {
        sink64_local(b, t, L.mat, L.fL, L.gL, vprev);  // includes syncthreads
    } else {
        __syncthreads();
    }

    const int r1 = t >> 2, lane = t & 3;
    const int i0 = off1[b * 65 + r1], i1 = off1[b * 65 + r1 + 1];
    const float* Keb = Ke + (size_t)b * kE * kE;
    const float* KpB = Kp + (size_t)b * kNN;
    int degLocal = 0;

    if constexpr (C == 1) {
        float acc = 0.f;
        for (int k = 0; k < n2; ++k) {
            int pk = L.jd2[k], j = (pk >> 8) & 255, dd2 = pk & 255;
            for (int m = i0 + lane; m < i1; m += 4) {
                int pi = L.il[m], i = (pi >> 8) & 255, dd1 = pi & 255;
                if (dd2 == r2 && dd1 == r1) continue;
                acc += Keb[(size_t)i * kE + j] * KpB[dd1 * 64 + dd2];
            }
        }
        acc += __shfl_xor(acc, 1);
        acc += __shfl_xor(acc, 2);
        if (lane == 0) L.msgT[r1][0] = acc;
        for (int m = i0 + lane; m < i1; m += 4) {
            int pi = L.il[m];
            if (!(pi >> 16)) continue;
            int i = (pi >> 8) & 255, dd1 = pi & 255;
            for (int k = 0; k < n2; ++k) {
                int pk = L.jd2[k];
                if (!(pk >> 16)) continue;
                int j = (pk >> 8) & 255, dd2 = pk & 255;
                float sum = 0.f;
                for (int mm = L.co1L[i]; mm < L.co1L[i + 1]; ++mm) {
                    const float* kr = Keb + (size_t)L.cl1L[mm] * kE;
                    for (int nn = L.co2L[j]; nn < L.co2L[j + 1]; ++nn)
                        sum += kr[L.cl2L[nn]];
                }
                if ((r2 * 64 + r1) != (dd2 * 64 + dd1) && sum > 0.0f) ++degLocal;
            }
        }
        degLocal += __shfl_xor(degLocal, 1);
        degLocal += __shfl_xor(degLocal, 2);
    } else {
        const float* xb = x + (size_t)b * kNN * kXS;
        float acc[5];
#pragma unroll
        for (int cc = 0; cc < 5; ++cc) acc[cc] = 0.f;
        for (int k = 0; k < n2; ++k) {
            int pk = L.jd2[k], j = (pk >> 8) & 255, dd2 = pk & 255;
            const float* xrow = xb + (size_t)(dd2 * 64) * kXS;
            for (int m = i0; m < i1; ++m) {
                int pi = L.il[m], dd1 = pi & 255;
                if (dd2 == r2 && dd1 == r1) continue;
                int i = (pi >> 8) & 255;
                float kv = Keb[(size_t)i * kE + j];
                // direct cached load: this lane's 4 channels of the x row
                float4 xv = *(const float4*)(xrow + dd1 * kXS + lane * 4);
                acc[0] += kv * xv.x;
                acc[1] += kv * xv.y;
                acc[2] += kv * xv.z;
                acc[3] += kv * xv.w;
                if (lane == 0) acc[4] += kv * L.mat[dd1][dd2];   // ss from LDS
            }
        }
        // channel mapping: acc[q] holds channel lane*4+q
#pragma unroll
        for (int q = 0; q < 4; ++q)
            L.msgT[r1][lane * 4 + q] = acc[q];
        if (lane == 0) L.msgT[r1][16] = acc[4];
    }
    __syncthreads();

    const int row = r2 * 64 + r1;
    const int idx = b * kNN + row;
    const float kd = KpB[r1 * 64 + r2];
    int degv;
    if constexpr (C == 1) {
        degv = degLocal;
        if (lane == 0) degcnt[idx] = degLocal;
    } else {
        degv = degcnt[idx];
    }
    const float dg = fmaxf((float)(degv + (kd > 0.f ? 1 : 0)), 1.f);
    float m[C];
    if constexpr (C == 1) {
        m[0] = (L.msgT[r1][0] + kd * kd) / dg;
    } else {
        float4 xa  = *(const float4*)(x + (size_t)idx * kXS + 0);
        float4 xb4 = *(const float4*)(x + (size_t)idx * kXS + 4);
        float4 xc4 = *(const float4*)(x + (size_t)idx * kXS + 8);
        float4 xd4 = *(const float4*)(x + (size_t)idx * kXS + 12);
        m[0]  = (L.msgT[r1][0]  + kd * xa.x) / dg;
        m[1]  = (L.msgT[r1][1]  + kd * xa.y) / dg;
        m[2]  = (L.msgT[r1][2]  + kd * xa.z) / dg;
        m[3]  = (L.msgT[r1][3]  + kd * xa.w) / dg;
        m[4]  = (L.msgT[r1][4]  + kd * xb4.x) / dg;
        m[5]  = (L.msgT[r1][5]  + kd * xb4.y) / dg;
        m[6]  = (L.msgT[r1][6]  + kd * xb4.z) / dg;
        m[7]  = (L.msgT[r1][7]  + kd * xb4.w) / dg;
        m[8]  = (L.msgT[r1][8]  + kd * xc4.x) / dg;
        m[9]  = (L.msgT[r1][9]  + kd * xc4.y) / dg;
        m[10] = (L.msgT[r1][10] + kd * xc4.z) / dg;
        m[11] = (L.msgT[r1][11] + kd * xc4.w) / dg;
        m[12] = (L.msgT[r1][12] + kd * xd4.x) / dg;
        m[13] = (L.msgT[r1][13] + kd * xd4.y) / dg;
        m[14] = (L.msgT[r1][14] + kd * xd4.z) / dg;
        m[15] = (L.msgT[r1][15] + kd * xd4.w) / dg;
        m[16] = (L.msgT[r1][16] + kd * L.mat[r1][r2]) / dg;   // own ss via LDS
    }
    float h[4];
    float vpart = 0.f;
#pragma unroll
    for (int ff = 0; ff < 4; ++ff) {
        int f = lane * 4 + ff;
        float a = L.bL[f];
#pragma unroll
        for (int c = 0; c < C; ++c) a += m[c] * L.WL[c * 16 + f];
        h[ff] = fmaxf(a, 0.f);
        vpart += h[ff] * L.SL[f];
    }
    if constexpr (!LASTP) {
        float4 hv; hv.x = h[0]; hv.y = h[1]; hv.z = h[2]; hv.w = h[3];
        *(float4*)(xn + (size_t)idx * kXS + lane * 4) = hv;
    } else {
        float vcp = h[0] * L.WcL[lane * 4 + 0] + h[1] * L.WcL[lane * 4 + 1]
                  + h[2] * L.WcL[lane * 4 + 2] + h[3] * L.WcL[lane * 4 + 3];
        vcp += __shfl_xor(vcp, 1);
        vcp += __shfl_xor(vcp, 2);
        if (lane == 0) vcbuf[idx] = vcp;
    }
    vpart += __shfl_xor(vpart, 1);
    vpart += __shfl_xor(vpart, 2);
    if (lane == 0) vout[idx] = vpart + L.c0v;
}

__global__ __launch_bounds__(256) void k_l0(
    const int* __restrict__ off1, const int* __restrict__ lst1,
    const int* __restrict__ off2, const int* __restrict__ lst2,
    const int* __restrict__ dst1, const int* __restrict__ dst2,
    const int* __restrict__ rep1g, const int* __restrict__ rep2g,
    const int* __restrict__ coff1, const int* __restrict__ coff2,
    const int* __restrict__ clst1, const int* __restrict__ clst2,
    const float* __restrict__ Ke, const float* __restrict__ Kp,
    int* __restrict__ degcnt,
    const float* __restrict__ W0, const float* __restrict__ b0,
    const float* __restrict__ S0, const float* __restrict__ c0,
    float* __restrict__ xA, float* __restrict__ vA)
{
    __shared__ SmemLayer L;
    layer_body<1, false>(blockIdx.x, threadIdx.x, L,
        off1, lst1, off2, lst2, dst1, dst2, rep1g, rep2g,
        coff1, coff2, clst1, clst2, Ke, nullptr, Kp, degcnt,
        W0, b0, S0, c0, nullptr, nullptr, xA, nullptr, vA);
}

__global__ __launch_bounds__(256) void k_l1(
    const int* __restrict__ off1, const int* __restrict__ lst1,
    const int* __restrict__ off2, const int* __restrict__ lst2,
    const int* __restrict__ dst1, const int* __restrict__ dst2,
    const float* __restrict__ Ke, const float* __restrict__ Kp,
    int* __restrict__ degcnt,
    const float* __restrict__ W1, const float* __restrict__ b1,
    const float* __restrict__ S1, const float* __restrict__ c1,
    const float* __restrict__ xA, const float* __restrict__ vA,
    float* __restrict__ xB, float* __restrict__ vB)
{
    __shared__ SmemLayer L;
    layer_body<17, false>(blockIdx.x, threadIdx.x, L,
        off1, lst1, off2, lst2, dst1, dst2, nullptr, nullptr,
        nullptr, nullptr, nullptr, nullptr, Ke, xA, Kp, degcnt,
        W1, b1, S1, c1, nullptr, vA, xB, nullptr, vB);
}

__global__ __launch_bounds__(256) void k_l2(
    const int* __restrict__ off1, const int* __restrict__ lst1,
    const int* __restrict__ off2, const int* __restrict__ lst2,
    const int* __restrict__ dst1, const int* __restrict__ dst2,
    const float* __restrict__ Ke, const float* __restrict__ Kp,
    int* __restrict__ degcnt,
    const float* __restrict__ W2, const float* __restrict__ b2,
    const float* __restrict__ S2, const float* __restrict__ c2,
    const float* __restrict__ Wc,
    const float* __restrict__ xB, const float* __restrict__ vB,
    float* __restrict__ vcbuf, float* __restrict__ vA)
{
    __shared__ SmemLayer L;
    layer_body<17, true>(blockIdx.x, threadIdx.x, L,
        off1, lst1, off2, lst2, dst1, dst2, nullptr, nullptr,
        nullptr, nullptr, nullptr, nullptr, Ke, xB, Kp, degcnt,
        W2, b2, S2, c2, Wc, vB, nullptr, vcbuf, vA);
}

// ===========================================================================
// K4: final — 8 blocks x 576 threads, fully static per-lane arrays (R11).
// ===========================================================================
struct __align__(16) SmemSinkF {
    float mat[65][68]; float fL[72], gL[72];
    float wred[9];
};

__global__ __launch_bounds__(576) void k_final(
    const float* __restrict__ vA, const float* __restrict__ vcbuf,
    const float* __restrict__ Wc, const float* __restrict__ bc,
    const float* __restrict__ binv,
    int* __restrict__ bars, float* __restrict__ out)
{
    const int b = blockIdx.x, t = threadIdx.x;
    __shared__ SmemSinkF S;

    for (int i = t; i < kNN; i += 576) {
        int q = i >> 6, p = i & 63;
        S.mat[p][q] = vA[b * kNN + i] * kTauInv;
    }
    if (t < 72) { S.fL[t] = 0.f; S.gL[t] = 0.f; }
    __syncthreads();

    const int r = t >> 3, s = t & 7;

    // ---- sink64: 8 lanes/row, fully static ----
    {
        const bool act = r < 64;
        const int rr = act ? r : 0;
        float Lr[8], Lc[8], tv[8];
#pragma unroll
        for (int k = 0; k < 8; ++k) {
            Lr[k] = S.mat[rr][s + 8 * k];
            Lc[k] = S.mat[s + 8 * k][rr];
        }
        __syncthreads();
        for (int it = 0; it < 10; ++it) {
            float mx = -1e30f;
#pragma unroll
            for (int k = 0; k < 8; ++k) { tv[k] = Lr[k] + S.gL[s + 8 * k]; mx = fmaxf(mx, tv[k]); }
            mx = fmaxf(mx, __shfl_xor(mx, 1));
            mx = fmaxf(mx, __shfl_xor(mx, 2));
            mx = fmaxf(mx, __shfl_xor(mx, 4));
            float sum = 0.f;
#pragma unroll
            for (int k = 0; k < 8; ++k) sum += __expf(tv[k] - mx);
            sum += __shfl_xor(sum, 1);
            sum += __shfl_xor(sum, 2);
            sum += __shfl_xor(sum, 4);
            if (act && s == 0) S.fL[r] = -(mx + __logf(sum));
            __syncthreads();
            mx = -1e30f;
#pragma unroll
            for (int k = 0; k < 8; ++k) { tv[k] = Lc[k] + S.fL[s + 8 * k]; mx = fmaxf(mx, tv[k]); }
            mx = fmaxf(mx, __shfl_xor(mx, 1));
            mx = fmaxf(mx, __shfl_xor(mx, 2));
            mx = fmaxf(mx, __shfl_xor(mx, 4));
            sum = 0.f;
#pragma unroll
            for (int k = 0; k < 8; ++k) sum += __expf(tv[k] - mx);
            sum += __shfl_xor(sum, 1);
            sum += __shfl_xor(sum, 2);
            sum += __shfl_xor(sum, 4);
            if (act && s == 0) S.gL[r] = -(mx + __logf(sum));
            __syncthreads();
        }
        if (act) {
            const float fr = S.fL[r];
#pragma unroll
            for (int k = 0; k < 8; ++k) {
                int q = s + 8 * k;
                S.mat[r][q] = __expf(Lr[k] + fr + S.gL[q]);   // ss prob
            }
        }
    }
    __syncthreads();

    // ---- build 65x65 log matrix in place ----
    {
        const float Wc16 = Wc[16], bcv = bc[0], binvv = binv[0];
        const float* vcb = vcbuf + (size_t)b * kNN;
        for (int idx = t; idx < 65 * 65; idx += 576) {
            int q = idx / 65, p = idx - q * 65;
            float v;
            if (p < 64 && q < 64)
                v = vcb[q * 64 + p] + S.mat[p][q] * Wc16 + bcv;
            else v = binvv;
            S.mat[p][q] = v;
        }
        if (t < 72) { S.fL[t] = 0.f; S.gL[t] = 0.f; }
    }
    __syncthreads();

    // ---- sink65: 8 lanes/row, 9th element static-guarded ----
    const bool act = r < 65;
    const int rr = act ? r : 0;
    float Lrow[9], Lcol[9], tv[9];
#pragma unroll
    for (int k = 0; k < 8; ++k) {
        Lrow[k] = S.mat[rr][s + 8 * k];
        Lcol[k] = S.mat[s + 8 * k][rr];
    }
    Lrow[8] = (s == 0) ? S.mat[rr][64] : -1e30f;
    Lcol[8] = (s == 0) ? S.mat[64][rr] : -1e30f;
    __syncthreads();

    for (int it = 0; it < 10; ++it) {
        float mx = -1e30f;
#pragma unroll
        for (int k = 0; k < 9; ++k) { tv[k] = Lrow[k] + S.gL[s + 8 * k]; mx = fmaxf(mx, tv[k]); }
        mx = fmaxf(mx, __shfl_xor(mx, 1));
        mx = fmaxf(mx, __shfl_xor(mx, 2));
        mx = fmaxf(mx, __shfl_xor(mx, 4));
        float sum = 0.f;
#pragma unroll
        for (int k = 0; k < 9; ++k) sum += __expf(tv[k] - mx);
        sum += __shfl_xor(sum, 1);
        sum += __shfl_xor(sum, 2);
        sum += __shfl_xor(sum, 4);
        if (act && s == 0) S.fL[r] = -(mx + __logf(sum));
        __syncthreads();
        mx = -1e30f;
#pragma unroll
        for (int k = 0; k < 9; ++k) { tv[k] = Lcol[k] + S.fL[s + 8 * k]; mx = fmaxf(mx, tv[k]); }
        mx = fmaxf(mx, __shfl_xor(mx, 1));
        mx = fmaxf(mx, __shfl_xor(mx, 2));
        mx = fmaxf(mx, __shfl_xor(mx, 4));
        sum = 0.f;
#pragma unroll
        for (int k = 0; k < 9; ++k) sum += __expf(tv[k] - mx);
        sum += __shfl_xor(sum, 1);
        sum += __shfl_xor(sum, 2);
        sum += __shfl_xor(sum, 4);
        if (act && s == 0) S.gL[r] = -(mx + __logf(sum));
        __syncthreads();
    }

    float ev[8];
    float lmax = 0.f;
    if (r < 64) {
        const float fr = S.fL[r];
#pragma unroll
        for (int k = 0; k < 8; ++k) {
            ev[k] = __expf(Lrow[k] + fr + S.gL[s + 8 * k]);
            lmax = fmaxf(lmax, ev[k]);
        }
    }
#pragma unroll
    for (int o = 32; o >= 1; o >>= 1) lmax = fmaxf(lmax, __shfl_xor(lmax, o));
    if ((t & 63) == 0) S.wred[t >> 6] = lmax;
    __syncthreads();
    int* mcnt = bars + 3584;
    int* gmax = bars + 3600;
    if (t == 0) {
        float mb = S.wred[0];
#pragma unroll
        for (int w = 1; w < 9; ++w) mb = fmaxf(mb, S.wred[w]);
        atomicMax(gmax, __float_as_int(mb));   // all values > 0
        asm volatile("s_waitcnt vmcnt(0)" ::: "memory");
        __hip_atomic_fetch_add(mcnt, 1, __ATOMIC_RELAXED, __HIP_MEMORY_SCOPE_AGENT);
        while (__hip_atomic_load(mcnt, __ATOMIC_RELAXED, __HIP_MEMORY_SCOPE_AGENT) < 8)
            __builtin_amdgcn_s_sleep(2);
    }
    __syncthreads();
    const float inv = 1.f / __int_as_float(
        __hip_atomic_load(gmax, __ATOMIC_RELAXED, __HIP_MEMORY_SCOPE_AGENT));
    if (r < 64) {
#pragma unroll
        for (int k = 0; k < 8; ++k)
            out[((size_t)b * kN + r) * kN + s + 8 * k] = ev[k] * inv;
    }
}

// ---------------------------------------------------------------------------
extern "C" void kernel_launch(void* const* d_in, const int* in_sizes, int n_in,
                              void* d_out, int out_size, void* d_ws, size_t ws_size,
                              hipStream_t stream)
{
    (void)in_sizes; (void)n_in; (void)out_size; (void)ws_size;

    const float* x1    = (const float*)d_in[0];
    const float* x2    = (const float*)d_in[1];
    const float* e1    = (const float*)d_in[2];
    const float* e2    = (const float*)d_in[3];
    const float* Wp    = (const float*)d_in[4];
    const float* bp    = (const float*)d_in[5];
    const float* gamma = (const float*)d_in[6];
    const float* beta  = (const float*)d_in[7];
    const float* W0 = (const float*)d_in[8];
    const float* b0 = (const float*)d_in[9];
    const float* S0 = (const float*)d_in[10];
    const float* c0 = (const float*)d_in[11];
    const float* W1 = (const float*)d_in[12];
    const float* b1 = (const float*)d_in[13];
    const float* S1 = (const float*)d_in[14];
    const float* c1 = (const float*)d_in[15];
    const float* W2 = (const float*)d_in[16];
    const float* b2 = (const float*)d_in[17];
    const float* S2 = (const float*)d_in[18];
    const float* c2 = (const float*)d_in[19];
    const float* Wc = (const float*)d_in[20];
    const float* bc = (const float*)d_in[21];
    const float* binv = (const float*)d_in[22];
    const int* src1 = (const int*)d_in[23];
    const int* dst1 = (const int*)d_in[24];
    const int* src2 = (const int*)d_in[25];
    const int* dst2 = (const int*)d_in[26];

    float* out = (float*)d_out;
    float* wsf = (float*)d_ws;

    float* hbuf  = wsf;                    // 1,048,576
    float* P     = hbuf + 1048576;         // 2,097,152 (2 x 4MB z-slices)
    float* Kp    = P + 2097152;            // 32,768
    float* Ke    = Kp + 32768;             // 294,912
    float* vA    = Ke + 294912;            // 32,768
    float* vB    = vA + 32768;             // 32,768
    float* xA    = vB + 32768;             // 524,288 (stride 16)
    float* xB    = xA + 524288;            // 524,288
    float* vcbuf = xB + 524288;            // 32,768
    int*   degcnt = (int*)(vcbuf + 32768); // 32,768
    int*   off1 = degcnt + 32768;          // 520
    int*   off2 = off1 + 520;              // 520
    int*   lst1 = off2 + 520;              // 1,536
    int*   lst2 = lst1 + 1536;             // 1,536
    int*   rep1g = lst2 + 1536;            // 1,536
    int*   rep2g = rep1g + 1536;           // 1,536
    int*   coff1 = rep2g + 1536;           // 1,544
    int*   coff2 = coff1 + 1544;           // 1,544
    int*   clst1 = coff2 + 1544;           // 1,536
    int*   clst2 = clst1 + 1536;           // 1,536
    float* stats = (float*)(clst2 + 1536); // 2,048 (zeroed by k_projcsr)
    int*   bars  = (int*)(stats + 2048);   // 4,096 (2 words zeroed by k_sim)

    k_projcsr<<<dim3(520), dim3(256), 0, stream>>>(
        x1, x2, e1, e2, Wp, src1, dst1, src2, dst2, P, stats,
        off1, off2, lst1, lst2, rep1g, rep2g, coff1, coff2, clst1, clst2);
    k_reduce<<<dim3(256), dim3(256), 0, stream>>>(P, bp, hbuf, stats);
    k_sim<<<dim3(320), dim3(256), 0, stream>>>(hbuf, stats, gamma, beta, Kp, Ke, bars);
    k_l0<<<dim3(512), dim3(256), 0, stream>>>(
        off1, lst1, off2, lst2, dst1, dst2, rep1g, rep2g,
        coff1, coff2, clst1, clst2, Ke, Kp, degcnt,
        W0, b0, S0, c0, xA, vA);
    k_l1<<<dim3(512), dim3(256), 0, stream>>>(
        off1, lst1, off2, lst2, dst1, dst2, Ke, Kp, degcnt,
        W1, b1, S1, c1, xA, vA, xB, vB);
    k_l2<<<dim3(512), dim3(256), 0, stream>>>(
        off1, lst1, off2, lst2, dst1, dst2, Ke, Kp, degcnt,
        W2, b2, S2, c2, Wc, xB, vB, vcbuf, vA);
    k_final<<<dim3(8), dim3(576), 0, stream>>>(vA, vcbuf, Wc, bc, binv, bars, out);
}

// Round 15
// 291.716 us; speedup vs baseline: 1.0115x; 1.0115x over previous
//
#include <hip/hip_runtime.h>

constexpr int kB   = 8;
constexpr int kN   = 64;
constexpr int kE   = 192;
constexpr int kDin = 1024;
constexpr int kDp  = 256;
constexpr int kNN  = 4096;
constexpr float kTauInv = 20.0f;
constexpr int kXS  = 16;     // x row stride (ss channel lives in LDS only)

typedef float vfloat4 __attribute__((ext_vector_type(4)));

// ===========================================================================
// K1: projection GEMM 64x64 tiles, z=2 split-K (blocks 0..511)
//     + CSR build (blocks 512..519).  CSR block b==0 also zeroes stats.
// ===========================================================================
struct SmemGemm { float As[2][16][68]; float Ws[2][16][68]; };
struct SmemCsr  {
    int km1[4096], km2[4096];
    short es1[kE], es2[kE], rp1[kE], rp2[kE];
    int cnt1[64], cnt2[64], pos1[64], pos2[64];
    int ccnt1[kE], ccnt2[kE], cpos1[kE], cpos2[kE];
};
union __align__(16) SmemK1 { SmemGemm g; SmemCsr csr; };

__global__ __launch_bounds__(256) void k_projcsr(
    const float* __restrict__ x1, const float* __restrict__ x2,
    const float* __restrict__ e1, const float* __restrict__ e2,
    const float* __restrict__ Wp,
    const int* __restrict__ src1, const int* __restrict__ dst1,
    const int* __restrict__ src2, const int* __restrict__ dst2,
    float* __restrict__ P, float* __restrict__ stats,
    int* __restrict__ off1, int* __restrict__ off2,
    int* __restrict__ lst1, int* __restrict__ lst2,
    int* __restrict__ rep1g, int* __restrict__ rep2g,
    int* __restrict__ coff1, int* __restrict__ coff2,
    int* __restrict__ clst1, int* __restrict__ clst2)
{
    const int bid = blockIdx.x, t = threadIdx.x;
    __shared__ SmemK1 u;

    if (bid < 512) {
        const int z = bid >> 8;                 // 0..1 K-half
        const int rt = (bid >> 2) & 63, ct = bid & 3;
        const int grow0 = rt * 64, col0 = ct * 64;
        const float* src; int lrow0;
        if (rt < 8)       { src = x1; lrow0 = grow0; }
        else if (rt < 16) { src = x2; lrow0 = grow0 - 512; }
        else if (rt < 40) { src = e1; lrow0 = grow0 - 1024; }
        else              { src = e2; lrow0 = grow0 - 2560; }

        const int tx = t & 15, ty = t >> 4;
        const int arow = t >> 2, acol = (t & 3) * 4;
        const int wrow = t >> 4, wcol = (t & 15) * 4;

        const float* Abase = src + (size_t)(lrow0 + arow) * kDin + z * 512 + acol;
        const float* Wbase = Wp + (size_t)(z * 512 + wrow) * kDp + col0 + wcol;

        float4 a4 = *(const float4*)Abase;
        float4 w4 = *(const float4*)Wbase;
        float acc[4][4] = {};

        for (int c = 0; c < 32; ++c) {
            const int cur = c & 1;
            u.g.As[cur][acol + 0][arow] = a4.x;
            u.g.As[cur][acol + 1][arow] = a4.y;
            u.g.As[cur][acol + 2][arow] = a4.z;
            u.g.As[cur][acol + 3][arow] = a4.w;
            *(float4*)&u.g.Ws[cur][wrow][wcol] = w4;
            __syncthreads();
            if (c < 31) {
                a4 = *(const float4*)(Abase + (c + 1) * 16);
                w4 = *(const float4*)(Wbase + (size_t)(c + 1) * 16 * kDp);
            }
#pragma unroll
            for (int kk = 0; kk < 16; ++kk) {
                float4 av = *(const float4*)&u.g.As[cur][kk][ty * 4];
                float4 wv = *(const float4*)&u.g.Ws[cur][kk][tx * 4];
                float a[4] = {av.x, av.y, av.z, av.w};
                float w[4] = {wv.x, wv.y, wv.z, wv.w};
#pragma unroll
                for (int i = 0; i < 4; ++i)
#pragma unroll
                    for (int j = 0; j < 4; ++j)
                        acc[i][j] += a[i] * w[j];
            }
        }
        float* Pz = P + (size_t)z * 1048576;
#pragma unroll
        for (int i = 0; i < 4; ++i) {
            const int row = grow0 + ty * 4 + i;
            float4 v;
            v.x = acc[i][0]; v.y = acc[i][1]; v.z = acc[i][2]; v.w = acc[i][3];
            *(float4*)&Pz[(size_t)row * kDp + col0 + tx * 4] = v;
        }
    } else {
        const int b = bid - 512;
        auto& C = u.csr;
        if (b == 0)
            for (int i = t; i < 2048; i += 256) stats[i] = 0.f;
        for (int i = t; i < 4096; i += 256) {
            C.km1[i] = 0x7fffffff; C.km2[i] = 0x7fffffff;
        }
        if (t < 64) { C.cnt1[t] = 0; C.cnt2[t] = 0; }
        for (int i = t; i < kE; i += 256) { C.ccnt1[i] = 0; C.ccnt2[i] = 0; }
        __syncthreads();
        if (t < kE) {
            int v1 = src1[b * kE + t], v2 = src2[b * kE + t];
            C.es1[t] = (short)v1; C.es2[t] = (short)v2;
            atomicAdd(&C.cnt1[v1], 1);
            atomicAdd(&C.cnt2[v2], 1);
            atomicMin(&C.km1[v1 * 64 + dst1[b * kE + t]], t);
            atomicMin(&C.km2[v2 * 64 + dst2[b * kE + t]], t);
        }
        __syncthreads();
        if (t < kE) {
            int r1 = C.km1[C.es1[t] * 64 + dst1[b * kE + t]];
            int r2 = C.km2[C.es2[t] * 64 + dst2[b * kE + t]];
            C.rp1[t] = (short)r1; C.rp2[t] = (short)r2;
            rep1g[b * kE + t] = r1; rep2g[b * kE + t] = r2;
            atomicAdd(&C.ccnt1[r1], 1);
            atomicAdd(&C.ccnt2[r2], 1);
        }
        __syncthreads();
        if (t == 0) {
            int a = 0, c = 0;
            for (int v = 0; v < 64; ++v) { C.pos1[v] = a; a += C.cnt1[v]; C.pos2[v] = c; c += C.cnt2[v]; }
            a = 0; c = 0;
            for (int v = 0; v < kE; ++v) { C.cpos1[v] = a; a += C.ccnt1[v]; C.cpos2[v] = c; c += C.ccnt2[v]; }
        }
        __syncthreads();
        if (t < 64) { off1[b * 65 + t] = C.pos1[t]; off2[b * 65 + t] = C.pos2[t]; }
        if (t == 0) { off1[b * 65 + 64] = kE; off2[b * 65 + 64] = kE; }
        if (t < kE) { coff1[b * 193 + t] = C.cpos1[t]; coff2[b * 193 + t] = C.cpos2[t]; }
        if (t == 0) { coff1[b * 193 + kE] = kE; coff2[b * 193 + kE] = kE; }
        __syncthreads();
        if (t < kE) {
            int p = atomicAdd(&C.pos1[C.es1[t]], 1); lst1[b * kE + p] = t;
            int q = atomicAdd(&C.pos2[C.es2[t]], 1); lst2[b * kE + q] = t;
            int cp = atomicAdd(&C.cpos1[C.rp1[t]], 1); clst1[b * kE + cp] = t;
            int cq = atomicAdd(&C.cpos2[C.rp2[t]], 1); clst2[b * kE + cq] = t;
        }
    }
}

// ===========================================================================
// K1b: reduce split-K partials + bias -> hbuf, accumulate BN stats.
// ===========================================================================
__global__ __launch_bounds__(256) void k_reduce(
    const float* __restrict__ P, const float* __restrict__ bp,
    float* __restrict__ hbuf, float* __restrict__ stats)
{
    const int t = threadIdx.x;
    const int r0 = blockIdx.x * 16;
    const int seg = (r0 < 512) ? 0 : (r0 < 1024 ? 1 : (r0 < 2560 ? 2 : 3));
    const float bb = bp[t];
    float s = 0.f, s2 = 0.f;
#pragma unroll
    for (int rr = 0; rr < 16; ++rr) {
        size_t o = (size_t)(r0 + rr) * kDp + t;
        float v = P[o] + P[o + 1048576] + bb;
        hbuf[o] = v;
        s += v; s2 += v * v;
    }
    atomicAdd(&stats[seg * 512 + t], s);
    atomicAdd(&stats[seg * 512 + 256 + t], s2);
}

// ===========================================================================
// K2: similarity GEMMs with inline BN+ReLU+L2.  320 blocks.
// Block 0 zeroes the 2 barrier words used by k_final.
// ===========================================================================
struct __align__(16) SmemSim  {
    float Xs[32][36]; float Ys[32][36];
    float muX[256], isX[256], muY[256], isY[256];
    float ga[256], be[256];
    float scX[32], scY[32];
};

__global__ __launch_bounds__(256) void k_sim(
    const float* __restrict__ hbuf, const float* __restrict__ stats,
    const float* __restrict__ gamma, const float* __restrict__ beta,
    float* __restrict__ Kp, float* __restrict__ Ke,
    int* __restrict__ bars)
{
    const int bid = blockIdx.x, t = threadIdx.x;
    __shared__ SmemSim u;

    if (bid == 0 && t == 0) { bars[3584] = 0; bars[3600] = 0; }

    const int id = bid % 40, b = bid / 40;
    int mt, nt_, ldo, segX, segY, xrow0, yrow0; float* outp; float scale;
    if (id < 4) {
        mt = (id >> 1) * 32; nt_ = (id & 1) * 32; ldo = 64;
        xrow0 = b * 64; yrow0 = 512 + b * 64;
        segX = 0; segY = 1;
        outp = Kp + (size_t)b * 4096; scale = 1.0f;
    } else {
        int e = id - 4;
        mt = (e / 6) * 32; nt_ = (e % 6) * 32; ldo = 192;
        xrow0 = 1024 + b * 192; yrow0 = 2560 + b * 192;
        segX = 2; segY = 3;
        outp = Ke + (size_t)b * 36864; scale = 0.5f;
    }
    {
        const float n = (segX < 2) ? 512.f : 1536.f;
        float mu = stats[segX * 512 + t] / n;
        float var = stats[segX * 512 + 256 + t] / n - mu * mu;
        u.muX[t] = mu; u.isX[t] = rsqrtf(var + 1e-5f);
        mu = stats[segY * 512 + t] / n;
        var = stats[segY * 512 + 256 + t] / n - mu * mu;
        u.muY[t] = mu; u.isY[t] = rsqrtf(var + 1e-5f);
        u.ga[t] = gamma[t]; u.be[t] = beta[t];
    }
    __syncthreads();
    {
        const int ri = t >> 2, lane = t & 3;
        const bool isXr = ri < 32;
        const int grow = isXr ? (xrow0 + mt + ri) : (yrow0 + nt_ + (ri - 32));
        const float* mus = isXr ? u.muX : u.muY;
        const float* iss = isXr ? u.isX : u.isY;
        const float* hr = hbuf + (size_t)grow * kDp;
        float ss = 0.f;
        for (int c4 = 0; c4 < 16; ++c4) {
            int c = lane * 64 + c4 * 4;
            float4 v = *(const float4*)&hr[c];
            float p;
            p = fmaxf((v.x - mus[c+0]) * iss[c+0] * u.ga[c+0] + u.be[c+0], 0.f); ss += p * p;
            p = fmaxf((v.y - mus[c+1]) * iss[c+1] * u.ga[c+1] + u.be[c+1], 0.f); ss += p * p;
            p = fmaxf((v.z - mus[c+2]) * iss[c+2] * u.ga[c+2] + u.be[c+2], 0.f); ss += p * p;
            p = fmaxf((v.w - mus[c+3]) * iss[c+3] * u.ga[c+3] + u.be[c+3], 0.f); ss += p * p;
        }
        ss += __shfl_xor(ss, 1);
        ss += __shfl_xor(ss, 2);
        if (lane == 0) {
            float sc = 1.f / fmaxf(sqrtf(ss), 1e-12f);
            if (isXr) u.scX[ri] = sc; else u.scY[ri - 32] = sc;
        }
    }
    __syncthreads();
    const int row = t >> 3, kq = t & 7;
    const int ty = t >> 4, tx = t & 15;
    const float* Xp = hbuf + (size_t)(xrow0 + mt) * kDp;
    const float* Yp = hbuf + (size_t)(yrow0 + nt_) * kDp;
    float acc[2][2] = {};
    for (int k0 = 0; k0 < kDp; k0 += 32) {
        const int c = k0 + kq * 4;
        float4 xa = *(const float4*)(Xp + (size_t)row * kDp + c);
        float4 ya = *(const float4*)(Yp + (size_t)row * kDp + c);
        const float sx = u.scX[row], sy = u.scY[row];
        u.Xs[kq*4+0][row] = fmaxf((xa.x - u.muX[c+0]) * u.isX[c+0] * u.ga[c+0] + u.be[c+0], 0.f) * sx;
        u.Xs[kq*4+1][row] = fmaxf((xa.y - u.muX[c+1]) * u.isX[c+1] * u.ga[c+1] + u.be[c+1], 0.f) * sx;
        u.Xs[kq*4+2][row] = fmaxf((xa.z - u.muX[c+2]) * u.isX[c+2] * u.ga[c+2] + u.be[c+2], 0.f) * sx;
        u.Xs[kq*4+3][row] = fmaxf((xa.w - u.muX[c+3]) * u.isX[c+3] * u.ga[c+3] + u.be[c+3], 0.f) * sx;
        u.Ys[kq*4+0][row] = fmaxf((ya.x - u.muY[c+0]) * u.isY[c+0] * u.ga[c+0] + u.be[c+0], 0.f) * sy;
        u.Ys[kq*4+1][row] = fmaxf((ya.y - u.muY[c+1]) * u.isY[c+1] * u.ga[c+1] + u.be[c+1], 0.f) * sy;
        u.Ys[kq*4+2][row] = fmaxf((ya.z - u.muY[c+2]) * u.isY[c+2] * u.ga[c+2] + u.be[c+2], 0.f) * sy;
        u.Ys[kq*4+3][row] = fmaxf((ya.w - u.muY[c+3]) * u.isY[c+3] * u.ga[c+3] + u.be[c+3], 0.f) * sy;
        __syncthreads();
#pragma unroll
        for (int kk = 0; kk < 32; ++kk) {
            float2 xv = *(const float2*)&u.Xs[kk][ty * 2];
            float2 yv = *(const float2*)&u.Ys[kk][tx * 2];
            acc[0][0] += xv.x * yv.x; acc[0][1] += xv.x * yv.y;
            acc[1][0] += xv.y * yv.x; acc[1][1] += xv.y * yv.y;
        }
        __syncthreads();
    }
#pragma unroll
    for (int i = 0; i < 2; ++i)
#pragma unroll
        for (int j = 0; j < 2; ++j)
            outp[(size_t)(mt + ty * 2 + i) * ldo + nt_ + tx * 2 + j] = scale * acc[i][j];
}

// ===========================================================================
// K3a/b/c: one GNN layer per kernel (512 blocks each).
// R14 lesson: FETCH 9.1MB == Ke panel fetched once per XCD per batch
// (64 blocks/batch round-robin across 8 XCDs).  Fix: XCD-aware decode
// b = bid&7, r2 = bid>>3 — all 64 blocks of batch b land on one XCD,
// whose L2 then holds the batch's Ke/x/Kp/v (fetched from HBM once).
// Per-block computation is bit-identical; only the block->(b,r2) map moves.
// ===========================================================================
struct __align__(16) SmemLayer {
    float mat[64][68]; float fL[64], gL[64];
    float WL[17 * 16]; float bL[16], SL[16]; float c0v;
    float WcL[17];
    int jd2[kE]; int il[kE]; float msgT[64][18];
    int co1L[kE + 1], co2L[kE + 1];
    short cl1L[kE], cl2L[kE];
};

// Local per-block 64x64 sinkhorn (4-lane rows, static unrolls).
__device__ void sink64_local(int b, int t, float (*mat)[68], float* fL, float* gL,
                             const float* __restrict__ vin)
{
    const float4* v4 = (const float4*)(vin + b * kNN);
    for (int i = t; i < 1024; i += 256) {
        float4 v = v4[i];
        int idx = i * 4;
        int q = idx >> 6, p = idx & 63;
        mat[p][q]     = v.x * kTauInv;
        mat[p + 1][q] = v.y * kTauInv;
        mat[p + 2][q] = v.z * kTauInv;
        mat[p + 3][q] = v.w * kTauInv;
    }
    if (t < 64) { fL[t] = 0.f; gL[t] = 0.f; }
    __syncthreads();
    const int r = t >> 2, s = t & 3;
    float tv[16];
    for (int it = 0; it < 10; ++it) {
        float mx = -1e30f;
#pragma unroll
        for (int k = 0; k < 16; ++k) {
            float v = mat[r][s + 4 * k] + gL[s + 4 * k];
            tv[k] = v; mx = fmaxf(mx, v);
        }
        mx = fmaxf(mx, __shfl_xor(mx, 1));
        mx = fmaxf(mx, __shfl_xor(mx, 2));
        float sum = 0.f;
#pragma unroll
        for (int k = 0; k < 16; ++k) sum += __expf(tv[k] - mx);
        sum += __shfl_xor(sum, 1);
        sum += __shfl_xor(sum, 2);
        if (s == 0) fL[r] = -(mx + __logf(sum));
        __syncthreads();
        mx = -1e30f;
#pragma unroll
        for (int k = 0; k < 16; ++k) {
            float v = mat[s + 4 * k][r] + fL[s + 4 * k];
            tv[k] = v; mx = fmaxf(mx, v);
        }
        mx = fmaxf(mx, __shfl_xor(mx, 1));
        mx = fmaxf(mx, __shfl_xor(mx, 2));
        sum = 0.f;
#pragma unroll
        for (int k = 0; k < 16; ++k) sum += __expf(tv[k] - mx);
        sum += __shfl_xor(sum, 1);
        sum += __shfl_xor(sum, 2);
        if (s == 0) gL[r] = -(mx + __logf(sum));
        __syncthreads();
    }
    const float fr = fL[r];
#pragma unroll
    for (int k = 0; k < 16; ++k) {
        int q = s + 4 * k;
        mat[r][q] = __expf(mat[r][q] + fr + gL[q]);
    }
    __syncthreads();
}

template <int C, bool LASTP>
__device__ void layer_body(int bid, int t, SmemLayer& L,
    const int* __restrict__ off1, const int* __restrict__ lst1,
    const int* __restrict__ off2, const int* __restrict__ lst2,
    const int* __restrict__ d1, const int* __restrict__ d2,
    const int* __restrict__ rep1g, const int* __restrict__ rep2g,
    const int* __restrict__ coff1, const int* __restrict__ coff2,
    const int* __restrict__ clst1, const int* __restrict__ clst2,
    const float* __restrict__ Ke, const float* __restrict__ x,
    const float* __restrict__ Kp, int* __restrict__ degcnt,
    const float* __restrict__ W, const float* __restrict__ bb,
    const float* __restrict__ S, const float* __restrict__ c0,
    const float* __restrict__ Wc,
    const float* __restrict__ vprev, float* __restrict__ xn,
    float* __restrict__ vcbuf, float* __restrict__ vout)
{
    // XCD-aware decode: same-batch blocks share bid%8 -> same XCD L2.
    const int b = bid & 7, r2 = bid >> 3;
    for (int k = t; k < C * 16; k += 256) L.WL[k] = W[k];
    if (t < 16) { L.bL[t] = bb[t]; L.SL[t] = S[t]; }
    if (t == 0) L.c0v = c0[0];
    if (LASTP && t < 17) L.WcL[t] = Wc[t];
    const int j0 = off2[b * 65 + r2];
    const int n2 = off2[b * 65 + r2 + 1] - j0;
    for (int k = t; k < n2; k += 256) {
        int j = lst2[b * kE + j0 + k];
        int v = (j << 8) | d2[b * kE + j];
        if (C == 1 && rep2g[b * kE + j] == j) v |= 1 << 16;
        L.jd2[k] = v;
    }
    for (int k = t; k < kE; k += 256) {
        int i = lst1[b * kE + k];
        int v = (i << 8) | d1[b * kE + i];
        if (C == 1 && rep1g[b * kE + i] == i) v |= 1 << 16;
        L.il[k] = v;
    }
    if constexpr (C == 1) {
        for (int k = t; k < kE + 1; k += 256) {
            L.co1L[k] = coff1[b * 193 + k];
            L.co2L[k] = coff2[b * 193 + k];
        }
        for (int k = t; k < kE; k += 256) {
            L.cl1L[k] = (short)clst1[b * kE + k];
            L.cl2L[k] = (short)clst2[b * kE + k];
        }
    }
    if constexpr (C == 17) {
        sink64_local(b, t, L.mat, L.fL, L.gL, vprev);  // includes syncthreads
    } else {
        __syncthreads();
    }

    const int r1 = t >> 2, lane = t & 3;
    const int i0 = off1[b * 65 + r1], i1 = off1[b * 65 + r1 + 1];
    const float* Keb = Ke + (size_t)b * kE * kE;
    const float* KpB = Kp + (size_t)b * kNN;
    int degLocal = 0;

    if constexpr (C == 1) {
        float acc = 0.f;
        for (int k = 0; k < n2; ++k) {
            int pk = L.jd2[k], j = (pk >> 8) & 255, dd2 = pk & 255;
            for (int m = i0 + lane; m < i1; m += 4) {
                int pi = L.il[m], i = (pi >> 8) & 255, dd1 = pi & 255;
                if (dd2 == r2 && dd1 == r1) continue;
                acc += Keb[(size_t)i * kE + j] * KpB[dd1 * 64 + dd2];
            }
        }
        acc += __shfl_xor(acc, 1);
        acc += __shfl_xor(acc, 2);
        if (lane == 0) L.msgT[r1][0] = acc;
        for (int m = i0 + lane; m < i1; m += 4) {
            int pi = L.il[m];
            if (!(pi >> 16)) continue;
            int i = (pi >> 8) & 255, dd1 = pi & 255;
            for (int k = 0; k < n2; ++k) {
                int pk = L.jd2[k];
                if (!(pk >> 16)) continue;
                int j = (pk >> 8) & 255, dd2 = pk & 255;
                float sum = 0.f;
                for (int mm = L.co1L[i]; mm < L.co1L[i + 1]; ++mm) {
                    const float* kr = Keb + (size_t)L.cl1L[mm] * kE;
                    for (int nn = L.co2L[j]; nn < L.co2L[j + 1]; ++nn)
                        sum += kr[L.cl2L[nn]];
                }
                if ((r2 * 64 + r1) != (dd2 * 64 + dd1) && sum > 0.0f) ++degLocal;
            }
        }
        degLocal += __shfl_xor(degLocal, 1);
        degLocal += __shfl_xor(degLocal, 2);
    } else {
        const float* xb = x + (size_t)b * kNN * kXS;
        float acc[5];
#pragma unroll
        for (int cc = 0; cc < 5; ++cc) acc[cc] = 0.f;
        for (int k = 0; k < n2; ++k) {
            int pk = L.jd2[k], j = (pk >> 8) & 255, dd2 = pk & 255;
            const float* xrow = xb + (size_t)(dd2 * 64) * kXS;
            for (int m = i0; m < i1; ++m) {
                int pi = L.il[m], dd1 = pi & 255;
                if (dd2 == r2 && dd1 == r1) continue;
                int i = (pi >> 8) & 255;
                float kv = Keb[(size_t)i * kE + j];
                float4 xv = *(const float4*)(xrow + dd1 * kXS + lane * 4);
                acc[0] += kv * xv.x;
                acc[1] += kv * xv.y;
                acc[2] += kv * xv.z;
                acc[3] += kv * xv.w;
                if (lane == 0) acc[4] += kv * L.mat[dd1][dd2];   // ss from LDS
            }
        }
#pragma unroll
        for (int q = 0; q < 4; ++q)
            L.msgT[r1][lane * 4 + q] = acc[q];
        if (lane == 0) L.msgT[r1][16] = acc[4];
    }
    __syncthreads();

    const int row = r2 * 64 + r1;
    const int idx = b * kNN + row;
    const float kd = KpB[r1 * 64 + r2];
    int degv;
    if constexpr (C == 1) {
        degv = degLocal;
        if (lane == 0) degcnt[idx] = degLocal;
    } else {
        degv = degcnt[idx];
    }
    const float dg = fmaxf((float)(degv + (kd > 0.f ? 1 : 0)), 1.f);
    float m[C];
    if constexpr (C == 1) {
        m[0] = (L.msgT[r1][0] + kd * kd) / dg;
    } else {
        float4 xa  = *(const float4*)(x + (size_t)idx * kXS + 0);
        float4 xb4 = *(const float4*)(x + (size_t)idx * kXS + 4);
        float4 xc4 = *(const float4*)(x + (size_t)idx * kXS + 8);
        float4 xd4 = *(const float4*)(x + (size_t)idx * kXS + 12);
        m[0]  = (L.msgT[r1][0]  + kd * xa.x) / dg;
        m[1]  = (L.msgT[r1][1]  + kd * xa.y) / dg;
        m[2]  = (L.msgT[r1][2]  + kd * xa.z) / dg;
        m[3]  = (L.msgT[r1][3]  + kd * xa.w) / dg;
        m[4]  = (L.msgT[r1][4]  + kd * xb4.x) / dg;
        m[5]  = (L.msgT[r1][5]  + kd * xb4.y) / dg;
        m[6]  = (L.msgT[r1][6]  + kd * xb4.z) / dg;
        m[7]  = (L.msgT[r1][7]  + kd * xb4.w) / dg;
        m[8]  = (L.msgT[r1][8]  + kd * xc4.x) / dg;
        m[9]  = (L.msgT[r1][9]  + kd * xc4.y) / dg;
        m[10] = (L.msgT[r1][10] + kd * xc4.z) / dg;
        m[11] = (L.msgT[r1][11] + kd * xc4.w) / dg;
        m[12] = (L.msgT[r1][12] + kd * xd4.x) / dg;
        m[13] = (L.msgT[r1][13] + kd * xd4.y) / dg;
        m[14] = (L.msgT[r1][14] + kd * xd4.z) / dg;
        m[15] = (L.msgT[r1][15] + kd * xd4.w) / dg;
        m[16] = (L.msgT[r1][16] + kd * L.mat[r1][r2]) / dg;   // own ss via LDS
    }
    float h[4];
    float vpart = 0.f;
#pragma unroll
    for (int ff = 0; ff < 4; ++ff) {
        int f = lane * 4 + ff;
        float a = L.bL[f];
#pragma unroll
        for (int c = 0; c < C; ++c) a += m[c] * L.WL[c * 16 + f];
        h[ff] = fmaxf(a, 0.f);
        vpart += h[ff] * L.SL[f];
    }
    if constexpr (!LASTP) {
        float4 hv; hv.x = h[0]; hv.y = h[1]; hv.z = h[2]; hv.w = h[3];
        *(float4*)(xn + (size_t)idx * kXS + lane * 4) = hv;
    } else {
        float vcp = h[0] * L.WcL[lane * 4 + 0] + h[1] * L.WcL[lane * 4 + 1]
                  + h[2] * L.WcL[lane * 4 + 2] + h[3] * L.WcL[lane * 4 + 3];
        vcp += __shfl_xor(vcp, 1);
        vcp += __shfl_xor(vcp, 2);
        if (lane == 0) vcbuf[idx] = vcp;
    }
    vpart += __shfl_xor(vpart, 1);
    vpart += __shfl_xor(vpart, 2);
    if (lane == 0) vout[idx] = vpart + L.c0v;
}

__global__ __launch_bounds__(256) void k_l0(
    const int* __restrict__ off1, const int* __restrict__ lst1,
    const int* __restrict__ off2, const int* __restrict__ lst2,
    const int* __restrict__ dst1, const int* __restrict__ dst2,
    const int* __restrict__ rep1g, const int* __restrict__ rep2g,
    const int* __restrict__ coff1, const int* __restrict__ coff2,
    const int* __restrict__ clst1, const int* __restrict__ clst2,
    const float* __restrict__ Ke, const float* __restrict__ Kp,
    int* __restrict__ degcnt,
    const float* __restrict__ W0, const float* __restrict__ b0,
    const float* __restrict__ S0, const float* __restrict__ c0,
    float* __restrict__ xA, float* __restrict__ vA)
{
    __shared__ SmemLayer L;
    layer_body<1, false>(blockIdx.x, threadIdx.x, L,
        off1, lst1, off2, lst2, dst1, dst2, rep1g, rep2g,
        coff1, coff2, clst1, clst2, Ke, nullptr, Kp, degcnt,
        W0, b0, S0, c0, nullptr, nullptr, xA, nullptr, vA);
}

__global__ __launch_bounds__(256) void k_l1(
    const int* __restrict__ off1, const int* __restrict__ lst1,
    const int* __restrict__ off2, const int* __restrict__ lst2,
    const int* __restrict__ dst1, const int* __restrict__ dst2,
    const float* __restrict__ Ke, const float* __restrict__ Kp,
    int* __restrict__ degcnt,
    const float* __restrict__ W1, const float* __restrict__ b1,
    const float* __restrict__ S1, const float* __restrict__ c1,
    const float* __restrict__ xA, const float* __restrict__ vA,
    float* __restrict__ xB, float* __restrict__ vB)
{
    __shared__ SmemLayer L;
    layer_body<17, false>(blockIdx.x, threadIdx.x, L,
        off1, lst1, off2, lst2, dst1, dst2, nullptr, nullptr,
        nullptr, nullptr, nullptr, nullptr, Ke, xA, Kp, degcnt,
        W1, b1, S1, c1, nullptr, vA, xB, nullptr, vB);
}

__global__ __launch_bounds__(256) void k_l2(
    const int* __restrict__ off1, const int* __restrict__ lst1,
    const int* __restrict__ off2, const int* __restrict__ lst2,
    const int* __restrict__ dst1, const int* __restrict__ dst2,
    const float* __restrict__ Ke, const float* __restrict__ Kp,
    int* __restrict__ degcnt,
    const float* __restrict__ W2, const float* __restrict__ b2,
    const float* __restrict__ S2, const float* __restrict__ c2,
    const float* __restrict__ Wc,
    const float* __restrict__ xB, const float* __restrict__ vB,
    float* __restrict__ vcbuf, float* __restrict__ vA)
{
    __shared__ SmemLayer L;
    layer_body<17, true>(blockIdx.x, threadIdx.x, L,
        off1, lst1, off2, lst2, dst1, dst2, nullptr, nullptr,
        nullptr, nullptr, nullptr, nullptr, Ke, xB, Kp, degcnt,
        W2, b2, S2, c2, Wc, vB, nullptr, vcbuf, vA);
}

// ===========================================================================
// K4: final — 8 blocks x 576 threads, fully static per-lane arrays (R11).
// ===========================================================================
struct __align__(16) SmemSinkF {
    float mat[65][68]; float fL[72], gL[72];
    float wred[9];
};

__global__ __launch_bounds__(576) void k_final(
    const float* __restrict__ vA, const float* __restrict__ vcbuf,
    const float* __restrict__ Wc, const float* __restrict__ bc,
    const float* __restrict__ binv,
    int* __restrict__ bars, float* __restrict__ out)
{
    const int b = blockIdx.x, t = threadIdx.x;
    __shared__ SmemSinkF S;

    for (int i = t; i < kNN; i += 576) {
        int q = i >> 6, p = i & 63;
        S.mat[p][q] = vA[b * kNN + i] * kTauInv;
    }
    if (t < 72) { S.fL[t] = 0.f; S.gL[t] = 0.f; }
    __syncthreads();

    const int r = t >> 3, s = t & 7;

    // ---- sink64: 8 lanes/row, fully static ----
    {
        const bool act = r < 64;
        const int rr = act ? r : 0;
        float Lr[8], Lc[8], tv[8];
#pragma unroll
        for (int k = 0; k < 8; ++k) {
            Lr[k] = S.mat[rr][s + 8 * k];
            Lc[k] = S.mat[s + 8 * k][rr];
        }
        __syncthreads();
        for (int it = 0; it < 10; ++it) {
            float mx = -1e30f;
#pragma unroll
            for (int k = 0; k < 8; ++k) { tv[k] = Lr[k] + S.gL[s + 8 * k]; mx = fmaxf(mx, tv[k]); }
            mx = fmaxf(mx, __shfl_xor(mx, 1));
            mx = fmaxf(mx, __shfl_xor(mx, 2));
            mx = fmaxf(mx, __shfl_xor(mx, 4));
            float sum = 0.f;
#pragma unroll
            for (int k = 0; k < 8; ++k) sum += __expf(tv[k] - mx);
            sum += __shfl_xor(sum, 1);
            sum += __shfl_xor(sum, 2);
            sum += __shfl_xor(sum, 4);
            if (act && s == 0) S.fL[r] = -(mx + __logf(sum));
            __syncthreads();
            mx = -1e30f;
#pragma unroll
            for (int k = 0; k < 8; ++k) { tv[k] = Lc[k] + S.fL[s + 8 * k]; mx = fmaxf(mx, tv[k]); }
            mx = fmaxf(mx, __shfl_xor(mx, 1));
            mx = fmaxf(mx, __shfl_xor(mx, 2));
            mx = fmaxf(mx, __shfl_xor(mx, 4));
            sum = 0.f;
#pragma unroll
            for (int k = 0; k < 8; ++k) sum += __expf(tv[k] - mx);
            sum += __shfl_xor(sum, 1);
            sum += __shfl_xor(sum, 2);
            sum += __shfl_xor(sum, 4);
            if (act && s == 0) S.gL[r] = -(mx + __logf(sum));
            __syncthreads();
        }
        if (act) {
            const float fr = S.fL[r];
#pragma unroll
            for (int k = 0; k < 8; ++k) {
                int q = s + 8 * k;
                S.mat[r][q] = __expf(Lr[k] + fr + S.gL[q]);   // ss prob
            }
        }
    }
    __syncthreads();

    // ---- build 65x65 log matrix in place ----
    {
        const float Wc16 = Wc[16], bcv = bc[0], binvv = binv[0];
        const float* vcb = vcbuf + (size_t)b * kNN;
        for (int idx = t; idx < 65 * 65; idx += 576) {
            int q = idx / 65, p = idx - q * 65;
            float v;
            if (p < 64 && q < 64)
                v = vcb[q * 64 + p] + S.mat[p][q] * Wc16 + bcv;
            else v = binvv;
            S.mat[p][q] = v;
        }
        if (t < 72) { S.fL[t] = 0.f; S.gL[t] = 0.f; }
    }
    __syncthreads();

    // ---- sink65: 8 lanes/row, 9th element static-guarded ----
    const bool act = r < 65;
    const int rr = act ? r : 0;
    float Lrow[9], Lcol[9], tv[9];
#pragma unroll
    for (int k = 0; k < 8; ++k) {
        Lrow[k] = S.mat[rr][s + 8 * k];
        Lcol[k] = S.mat[s + 8 * k][rr];
    }
    Lrow[8] = (s == 0) ? S.mat[rr][64] : -1e30f;
    Lcol[8] = (s == 0) ? S.mat[64][rr] : -1e30f;
    __syncthreads();

    for (int it = 0; it < 10; ++it) {
        float mx = -1e30f;
#pragma unroll
        for (int k = 0; k < 9; ++k) { tv[k] = Lrow[k] + S.gL[s + 8 * k]; mx = fmaxf(mx, tv[k]); }
        mx = fmaxf(mx, __shfl_xor(mx, 1));
        mx = fmaxf(mx, __shfl_xor(mx, 2));
        mx = fmaxf(mx, __shfl_xor(mx, 4));
        float sum = 0.f;
#pragma unroll
        for (int k = 0; k < 9; ++k) sum += __expf(tv[k] - mx);
        sum += __shfl_xor(sum, 1);
        sum += __shfl_xor(sum, 2);
        sum += __shfl_xor(sum, 4);
        if (act && s == 0) S.fL[r] = -(mx + __logf(sum));
        __syncthreads();
        mx = -1e30f;
#pragma unroll
        for (int k = 0; k < 9; ++k) { tv[k] = Lcol[k] + S.fL[s + 8 * k]; mx = fmaxf(mx, tv[k]); }
        mx = fmaxf(mx, __shfl_xor(mx, 1));
        mx = fmaxf(mx, __shfl_xor(mx, 2));
        mx = fmaxf(mx, __shfl_xor(mx, 4));
        sum = 0.f;
#pragma unroll
        for (int k = 0; k < 9; ++k) sum += __expf(tv[k] - mx);
        sum += __shfl_xor(sum, 1);
        sum += __shfl_xor(sum, 2);
        sum += __shfl_xor(sum, 4);
        if (act && s == 0) S.gL[r] = -(mx + __logf(sum));
        __syncthreads();
    }

    float ev[8];
    float lmax = 0.f;
    if (r < 64) {
        const float fr = S.fL[r];
#pragma unroll
        for (int k = 0; k < 8; ++k) {
            ev[k] = __expf(Lrow[k] + fr + S.gL[s + 8 * k]);
            lmax = fmaxf(lmax, ev[k]);
        }
    }
#pragma unroll
    for (int o = 32; o >= 1; o >>= 1) lmax = fmaxf(lmax, __shfl_xor(lmax, o));
    if ((t & 63) == 0) S.wred[t >> 6] = lmax;
    __syncthreads();
    int* mcnt = bars + 3584;
    int* gmax = bars + 3600;
    if (t == 0) {
        float mb = S.wred[0];
#pragma unroll
        for (int w = 1; w < 9; ++w) mb = fmaxf(mb, S.wred[w]);
        atomicMax(gmax, __float_as_int(mb));   // all values > 0
        asm volatile("s_waitcnt vmcnt(0)" ::: "memory");
        __hip_atomic_fetch_add(mcnt, 1, __ATOMIC_RELAXED, __HIP_MEMORY_SCOPE_AGENT);
        while (__hip_atomic_load(mcnt, __ATOMIC_RELAXED, __HIP_MEMORY_SCOPE_AGENT) < 8)
            __builtin_amdgcn_s_sleep(2);
    }
    __syncthreads();
    const float inv = 1.f / __int_as_float(
        __hip_atomic_load(gmax, __ATOMIC_RELAXED, __HIP_MEMORY_SCOPE_AGENT));
    if (r < 64) {
#pragma unroll
        for (int k = 0; k < 8; ++k)
            out[((size_t)b * kN + r) * kN + s + 8 * k] = ev[k] * inv;
    }
}

// ---------------------------------------------------------------------------
extern "C" void kernel_launch(void* const* d_in, const int* in_sizes, int n_in,
                              void* d_out, int out_size, void* d_ws, size_t ws_size,
                              hipStream_t stream)
{
    (void)in_sizes; (void)n_in; (void)out_size; (void)ws_size;

    const float* x1    = (const float*)d_in[0];
    const float* x2    = (const float*)d_in[1];
    const float* e1    = (const float*)d_in[2];
    const float* e2    = (const float*)d_in[3];
    const float* Wp    = (const float*)d_in[4];
    const float* bp    = (const float*)d_in[5];
    const float* gamma = (const float*)d_in[6];
    const float* beta  = (const float*)d_in[7];
    const float* W0 = (const float*)d_in[8];
    const float* b0 = (const float*)d_in[9];
    const float* S0 = (const float*)d_in[10];
    const float* c0 = (const float*)d_in[11];
    const float* W1 = (const float*)d_in[12];
    const float* b1 = (const float*)d_in[13];
    const float* S1 = (const float*)d_in[14];
    const float* c1 = (const float*)d_in[15];
    const float* W2 = (const float*)d_in[16];
    const float* b2 = (const float*)d_in[17];
    const float* S2 = (const float*)d_in[18];
    const float* c2 = (const float*)d_in[19];
    const float* Wc = (const float*)d_in[20];
    const float* bc = (const float*)d_in[21];
    const float* binv = (const float*)d_in[22];
    const int* src1 = (const int*)d_in[23];
    const int* dst1 = (const int*)d_in[24];
    const int* src2 = (const int*)d_in[25];
    const int* dst2 = (const int*)d_in[26];

    float* out = (float*)d_out;
    float* wsf = (float*)d_ws;

    float* hbuf  = wsf;                    // 1,048,576
    float* P     = hbuf + 1048576;         // 2,097,152 (2 x 4MB z-slices)
    float* Kp    = P + 2097152;            // 32,768
    float* Ke    = Kp + 32768;             // 294,912
    float* vA    = Ke + 294912;            // 32,768
    float* vB    = vA + 32768;             // 32,768
    float* xA    = vB + 32768;             // 524,288 (stride 16)
    float* xB    = xA + 524288;            // 524,288
    float* vcbuf = xB + 524288;            // 32,768
    int*   degcnt = (int*)(vcbuf + 32768); // 32,768
    int*   off1 = degcnt + 32768;          // 520
    int*   off2 = off1 + 520;              // 520
    int*   lst1 = off2 + 520;              // 1,536
    int*   lst2 = lst1 + 1536;             // 1,536
    int*   rep1g = lst2 + 1536;            // 1,536
    int*   rep2g = rep1g + 1536;           // 1,536
    int*   coff1 = rep2g + 1536;           // 1,544
    int*   coff2 = coff1 + 1544;           // 1,544
    int*   clst1 = coff2 + 1544;           // 1,536
    int*   clst2 = clst1 + 1536;           // 1,536
    float* stats = (float*)(clst2 + 1536); // 2,048 (zeroed by k_projcsr)
    int*   bars  = (int*)(stats + 2048);   // 4,096 (2 words zeroed by k_sim)

    k_projcsr<<<dim3(520), dim3(256), 0, stream>>>(
        x1, x2, e1, e2, Wp, src1, dst1, src2, dst2, P, stats,
        off1, off2, lst1, lst2, rep1g, rep2g, coff1, coff2, clst1, clst2);
    k_reduce<<<dim3(256), dim3(256), 0, stream>>>(P, bp, hbuf, stats);
    k_sim<<<dim3(320), dim3(256), 0, stream>>>(hbuf, stats, gamma, beta, Kp, Ke, bars);
    k_l0<<<dim3(512), dim3(256), 0, stream>>>(
        off1, lst1, off2, lst2, dst1, dst2, rep1g, rep2g,
        coff1, coff2, clst1, clst2, Ke, Kp, degcnt,
        W0, b0, S0, c0, xA, vA);
    k_l1<<<dim3(512), dim3(256), 0, stream>>>(
        off1, lst1, off2, lst2, dst1, dst2, Ke, Kp, degcnt,
        W1, b1, S1, c1, xA, vA, xB, vB);
    k_l2<<<dim3(512), dim3(256), 0, stream>>>(
        off1, lst1, off2, lst2, dst1, dst2, Ke, Kp, degcnt,
        W2, b2, S2, c2, Wc, xB, vB, vcbuf, vA);
    k_final<<<dim3(8), dim3(576), 0, stream>>>(vA, vcbuf, Wc, bc, binv, bars, out);
}

// Round 16
// 287.438 us; speedup vs baseline: 1.0265x; 1.0149x over previous
//
#include <hip/hip_runtime.h>

constexpr int kB   = 8;
constexpr int kN   = 64;
constexpr int kE   = 192;
constexpr int kDin = 1024;
constexpr int kDp  = 256;
constexpr int kNN  = 4096;
constexpr float kTauInv = 20.0f;
constexpr int kXS  = 16;     // x row stride (ss channel lives in LDS only)

typedef float vfloat4 __attribute__((ext_vector_type(4)));

// ===========================================================================
// K1: projection GEMM 64x64 tiles, z=4 split-K (blocks 0..1023)
//     + CSR build (blocks 1024..1031).  CSR block b==0 also zeroes stats.
// R15 lesson: the 4 ct-blocks sharing an A-slice were round-robined onto 4
// XCDs -> A fetched ~2x (FETCH 33.9MB vs 17 ideal).  XCD-grouped decode puts
// them on ONE XCD; z=4 restores 4 blocks/CU for latency hiding (R9 lesson).
// ===========================================================================
struct SmemGemm { float As[2][16][68]; float Ws[2][16][68]; };
struct SmemCsr  {
    int km1[4096], km2[4096];
    short es1[kE], es2[kE], rp1[kE], rp2[kE];
    int cnt1[64], cnt2[64], pos1[64], pos2[64];
    int ccnt1[kE], ccnt2[kE], cpos1[kE], cpos2[kE];
};
union __align__(16) SmemK1 { SmemGemm g; SmemCsr csr; };

__global__ __launch_bounds__(256) void k_projcsr(
    const float* __restrict__ x1, const float* __restrict__ x2,
    const float* __restrict__ e1, const float* __restrict__ e2,
    const float* __restrict__ Wp,
    const int* __restrict__ src1, const int* __restrict__ dst1,
    const int* __restrict__ src2, const int* __restrict__ dst2,
    float* __restrict__ P, float* __restrict__ stats,
    int* __restrict__ off1, int* __restrict__ off2,
    int* __restrict__ lst1, int* __restrict__ lst2,
    int* __restrict__ rep1g, int* __restrict__ rep2g,
    int* __restrict__ coff1, int* __restrict__ coff2,
    int* __restrict__ clst1, int* __restrict__ clst2)
{
    const int bid = blockIdx.x, t = threadIdx.x;
    __shared__ SmemK1 u;

    if (bid < 1024) {
        // XCD-grouped decode: the 4 ct variants of one (z,rt) A-slice share
        // bid%8 -> same XCD L2 under round-robin dispatch.
        const int xcd = bid & 7;
        const int ct = (bid >> 3) & 3;
        const int p = (bid >> 5) * 8 + xcd;     // 0..255 slice id
        const int z = p >> 6;                   // 0..3 K-quarter
        const int rt = p & 63;
        const int grow0 = rt * 64, col0 = ct * 64;
        const float* src; int lrow0;
        if (rt < 8)       { src = x1; lrow0 = grow0; }
        else if (rt < 16) { src = x2; lrow0 = grow0 - 512; }
        else if (rt < 40) { src = e1; lrow0 = grow0 - 1024; }
        else              { src = e2; lrow0 = grow0 - 2560; }

        const int tx = t & 15, ty = t >> 4;
        const int arow = t >> 2, acol = (t & 3) * 4;
        const int wrow = t >> 4, wcol = (t & 15) * 4;

        const float* Abase = src + (size_t)(lrow0 + arow) * kDin + z * 256 + acol;
        const float* Wbase = Wp + (size_t)(z * 256 + wrow) * kDp + col0 + wcol;

        float4 a4 = *(const float4*)Abase;
        float4 w4 = *(const float4*)Wbase;
        float acc[4][4] = {};

        for (int c = 0; c < 16; ++c) {
            const int cur = c & 1;
            u.g.As[cur][acol + 0][arow] = a4.x;
            u.g.As[cur][acol + 1][arow] = a4.y;
            u.g.As[cur][acol + 2][arow] = a4.z;
            u.g.As[cur][acol + 3][arow] = a4.w;
            *(float4*)&u.g.Ws[cur][wrow][wcol] = w4;
            __syncthreads();
            if (c < 15) {
                a4 = *(const float4*)(Abase + (c + 1) * 16);
                w4 = *(const float4*)(Wbase + (size_t)(c + 1) * 16 * kDp);
            }
#pragma unroll
            for (int kk = 0; kk < 16; ++kk) {
                float4 av = *(const float4*)&u.g.As[cur][kk][ty * 4];
                float4 wv = *(const float4*)&u.g.Ws[cur][kk][tx * 4];
                float a[4] = {av.x, av.y, av.z, av.w};
                float w[4] = {wv.x, wv.y, wv.z, wv.w};
#pragma unroll
                for (int i = 0; i < 4; ++i)
#pragma unroll
                    for (int j = 0; j < 4; ++j)
                        acc[i][j] += a[i] * w[j];
            }
        }
        float* Pz = P + (size_t)z * 1048576;
#pragma unroll
        for (int i = 0; i < 4; ++i) {
            const int row = grow0 + ty * 4 + i;
            float4 v;
            v.x = acc[i][0]; v.y = acc[i][1]; v.z = acc[i][2]; v.w = acc[i][3];
            *(float4*)&Pz[(size_t)row * kDp + col0 + tx * 4] = v;
        }
    } else {
        const int b = bid - 1024;
        auto& C = u.csr;
        if (b == 0)
            for (int i = t; i < 2048; i += 256) stats[i] = 0.f;
        for (int i = t; i < 4096; i += 256) {
            C.km1[i] = 0x7fffffff; C.km2[i] = 0x7fffffff;
        }
        if (t < 64) { C.cnt1[t] = 0; C.cnt2[t] = 0; }
        for (int i = t; i < kE; i += 256) { C.ccnt1[i] = 0; C.ccnt2[i] = 0; }
        __syncthreads();
        if (t < kE) {
            int v1 = src1[b * kE + t], v2 = src2[b * kE + t];
            C.es1[t] = (short)v1; C.es2[t] = (short)v2;
            atomicAdd(&C.cnt1[v1], 1);
            atomicAdd(&C.cnt2[v2], 1);
            atomicMin(&C.km1[v1 * 64 + dst1[b * kE + t]], t);
            atomicMin(&C.km2[v2 * 64 + dst2[b * kE + t]], t);
        }
        __syncthreads();
        if (t < kE) {
            int r1 = C.km1[C.es1[t] * 64 + dst1[b * kE + t]];
            int r2 = C.km2[C.es2[t] * 64 + dst2[b * kE + t]];
            C.rp1[t] = (short)r1; C.rp2[t] = (short)r2;
            rep1g[b * kE + t] = r1; rep2g[b * kE + t] = r2;
            atomicAdd(&C.ccnt1[r1], 1);
            atomicAdd(&C.ccnt2[r2], 1);
        }
        __syncthreads();
        if (t == 0) {
            int a = 0, c = 0;
            for (int v = 0; v < 64; ++v) { C.pos1[v] = a; a += C.cnt1[v]; C.pos2[v] = c; c += C.cnt2[v]; }
            a = 0; c = 0;
            for (int v = 0; v < kE; ++v) { C.cpos1[v] = a; a += C.ccnt1[v]; C.cpos2[v] = c; c += C.ccnt2[v]; }
        }
        __syncthreads();
        if (t < 64) { off1[b * 65 + t] = C.pos1[t]; off2[b * 65 + t] = C.pos2[t]; }
        if (t == 0) { off1[b * 65 + 64] = kE; off2[b * 65 + 64] = kE; }
        if (t < kE) { coff1[b * 193 + t] = C.cpos1[t]; coff2[b * 193 + t] = C.cpos2[t]; }
        if (t == 0) { coff1[b * 193 + kE] = kE; coff2[b * 193 + kE] = kE; }
        __syncthreads();
        if (t < kE) {
            int p = atomicAdd(&C.pos1[C.es1[t]], 1); lst1[b * kE + p] = t;
            int q = atomicAdd(&C.pos2[C.es2[t]], 1); lst2[b * kE + q] = t;
            int cp = atomicAdd(&C.cpos1[C.rp1[t]], 1); clst1[b * kE + cp] = t;
            int cq = atomicAdd(&C.cpos2[C.rp2[t]], 1); clst2[b * kE + cq] = t;
        }
    }
}

// ===========================================================================
// K1b: reduce z=4 split-K partials + bias -> hbuf, accumulate BN stats.
// (R0-verified summation order: P0+P1+P2+P3+bias.)
// ===========================================================================
__global__ __launch_bounds__(256) void k_reduce(
    const float* __restrict__ P, const float* __restrict__ bp,
    float* __restrict__ hbuf, float* __restrict__ stats)
{
    const int t = threadIdx.x;
    const int r0 = blockIdx.x * 16;
    const int seg = (r0 < 512) ? 0 : (r0 < 1024 ? 1 : (r0 < 2560 ? 2 : 3));
    const float bb = bp[t];
    float s = 0.f, s2 = 0.f;
#pragma unroll
    for (int rr = 0; rr < 16; ++rr) {
        size_t o = (size_t)(r0 + rr) * kDp + t;
        float v = P[o] + P[o + 1048576] + P[o + 2097152] + P[o + 3145728] + bb;
        hbuf[o] = v;
        s += v; s2 += v * v;
    }
    atomicAdd(&stats[seg * 512 + t], s);
    atomicAdd(&stats[seg * 512 + 256 + t], s2);
}

// ===========================================================================
// K2: similarity GEMMs with inline BN+ReLU+L2.  320 blocks.
// Block 0 zeroes the 2 barrier words used by k_final.
// ===========================================================================
struct __align__(16) SmemSim  {
    float Xs[32][36]; float Ys[32][36];
    float muX[256], isX[256], muY[256], isY[256];
    float ga[256], be[256];
    float scX[32], scY[32];
};

__global__ __launch_bounds__(256) void k_sim(
    const float* __restrict__ hbuf, const float* __restrict__ stats,
    const float* __restrict__ gamma, const float* __restrict__ beta,
    float* __restrict__ Kp, float* __restrict__ Ke,
    int* __restrict__ bars)
{
    const int bid = blockIdx.x, t = threadIdx.x;
    __shared__ SmemSim u;

    if (bid == 0 && t == 0) { bars[3584] = 0; bars[3600] = 0; }

    const int id = bid % 40, b = bid / 40;
    int mt, nt_, ldo, segX, segY, xrow0, yrow0; float* outp; float scale;
    if (id < 4) {
        mt = (id >> 1) * 32; nt_ = (id & 1) * 32; ldo = 64;
        xrow0 = b * 64; yrow0 = 512 + b * 64;
        segX = 0; segY = 1;
        outp = Kp + (size_t)b * 4096; scale = 1.0f;
    } else {
        int e = id - 4;
        mt = (e / 6) * 32; nt_ = (e % 6) * 32; ldo = 192;
        xrow0 = 1024 + b * 192; yrow0 = 2560 + b * 192;
        segX = 2; segY = 3;
        outp = Ke + (size_t)b * 36864; scale = 0.5f;
    }
    {
        const float n = (segX < 2) ? 512.f : 1536.f;
        float mu = stats[segX * 512 + t] / n;
        float var = stats[segX * 512 + 256 + t] / n - mu * mu;
        u.muX[t] = mu; u.isX[t] = rsqrtf(var + 1e-5f);
        mu = stats[segY * 512 + t] / n;
        var = stats[segY * 512 + 256 + t] / n - mu * mu;
        u.muY[t] = mu; u.isY[t] = rsqrtf(var + 1e-5f);
        u.ga[t] = gamma[t]; u.be[t] = beta[t];
    }
    __syncthreads();
    {
        const int ri = t >> 2, lane = t & 3;
        const bool isXr = ri < 32;
        const int grow = isXr ? (xrow0 + mt + ri) : (yrow0 + nt_ + (ri - 32));
        const float* mus = isXr ? u.muX : u.muY;
        const float* iss = isXr ? u.isX : u.isY;
        const float* hr = hbuf + (size_t)grow * kDp;
        float ss = 0.f;
        for (int c4 = 0; c4 < 16; ++c4) {
            int c = lane * 64 + c4 * 4;
            float4 v = *(const float4*)&hr[c];
            float p;
            p = fmaxf((v.x - mus[c+0]) * iss[c+0] * u.ga[c+0] + u.be[c+0], 0.f); ss += p * p;
            p = fmaxf((v.y - mus[c+1]) * iss[c+1] * u.ga[c+1] + u.be[c+1], 0.f); ss += p * p;
            p = fmaxf((v.z - mus[c+2]) * iss[c+2] * u.ga[c+2] + u.be[c+2], 0.f); ss += p * p;
            p = fmaxf((v.w - mus[c+3]) * iss[c+3] * u.ga[c+3] + u.be[c+3], 0.f); ss += p * p;
        }
        ss += __shfl_xor(ss, 1);
        ss += __shfl_xor(ss, 2);
        if (lane == 0) {
            float sc = 1.f / fmaxf(sqrtf(ss), 1e-12f);
            if (isXr) u.scX[ri] = sc; else u.scY[ri - 32] = sc;
        }
    }
    __syncthreads();
    const int row = t >> 3, kq = t & 7;
    const int ty = t >> 4, tx = t & 15;
    const float* Xp = hbuf + (size_t)(xrow0 + mt) * kDp;
    const float* Yp = hbuf + (size_t)(yrow0 + nt_) * kDp;
    float acc[2][2] = {};
    for (int k0 = 0; k0 < kDp; k0 += 32) {
        const int c = k0 + kq * 4;
        float4 xa = *(const float4*)(Xp + (size_t)row * kDp + c);
        float4 ya = *(const float4*)(Yp + (size_t)row * kDp + c);
        const float sx = u.scX[row], sy = u.scY[row];
        u.Xs[kq*4+0][row] = fmaxf((xa.x - u.muX[c+0]) * u.isX[c+0] * u.ga[c+0] + u.be[c+0], 0.f) * sx;
        u.Xs[kq*4+1][row] = fmaxf((xa.y - u.muX[c+1]) * u.isX[c+1] * u.ga[c+1] + u.be[c+1], 0.f) * sx;
        u.Xs[kq*4+2][row] = fmaxf((xa.z - u.muX[c+2]) * u.isX[c+2] * u.ga[c+2] + u.be[c+2], 0.f) * sx;
        u.Xs[kq*4+3][row] = fmaxf((xa.w - u.muX[c+3]) * u.isX[c+3] * u.ga[c+3] + u.be[c+3], 0.f) * sx;
        u.Ys[kq*4+0][row] = fmaxf((ya.x - u.muY[c+0]) * u.isY[c+0] * u.ga[c+0] + u.be[c+0], 0.f) * sy;
        u.Ys[kq*4+1][row] = fmaxf((ya.y - u.muY[c+1]) * u.isY[c+1] * u.ga[c+1] + u.be[c+1], 0.f) * sy;
        u.Ys[kq*4+2][row] = fmaxf((ya.z - u.muY[c+2]) * u.isY[c+2] * u.ga[c+2] + u.be[c+2], 0.f) * sy;
        u.Ys[kq*4+3][row] = fmaxf((ya.w - u.muY[c+3]) * u.isY[c+3] * u.ga[c+3] + u.be[c+3], 0.f) * sy;
        __syncthreads();
#pragma unroll
        for (int kk = 0; kk < 32; ++kk) {
            float2 xv = *(const float2*)&u.Xs[kk][ty * 2];
            float2 yv = *(const float2*)&u.Ys[kk][tx * 2];
            acc[0][0] += xv.x * yv.x; acc[0][1] += xv.x * yv.y;
            acc[1][0] += xv.y * yv.x; acc[1][1] += xv.y * yv.y;
        }
        __syncthreads();
    }
#pragma unroll
    for (int i = 0; i < 2; ++i)
#pragma unroll
        for (int j = 0; j < 2; ++j)
            outp[(size_t)(mt + ty * 2 + i) * ldo + nt_ + tx * 2 + j] = scale * acc[i][j];
}

// ===========================================================================
// K3a/b/c: one GNN layer per kernel (512 blocks each), XCD-grouped decode
// (b = bid&7) so each batch's Ke/x/Kp/v stay in one XCD's L2 (R15-verified).
// ===========================================================================
struct __align__(16) SmemLayer {
    float mat[64][68]; float fL[64], gL[64];
    float WL[17 * 16]; float bL[16], SL[16]; float c0v;
    float WcL[17];
    int jd2[kE]; int il[kE]; float msgT[64][18];
    int co1L[kE + 1], co2L[kE + 1];
    short cl1L[kE], cl2L[kE];
};

// Local per-block 64x64 sinkhorn (4-lane rows, static unrolls).
__device__ void sink64_local(int b, int t, float (*mat)[68], float* fL, float* gL,
                             const float* __restrict__ vin)
{
    const float4* v4 = (const float4*)(vin + b * kNN);
    for (int i = t; i < 1024; i += 256) {
        float4 v = v4[i];
        int idx = i * 4;
        int q = idx >> 6, p = idx & 63;
        mat[p][q]     = v.x * kTauInv;
        mat[p + 1][q] = v.y * kTauInv;
        mat[p + 2][q] = v.z * kTauInv;
        mat[p + 3][q] = v.w * kTauInv;
    }
    if (t < 64) { fL[t] = 0.f; gL[t] = 0.f; }
    __syncthreads();
    const int r = t >> 2, s = t & 3;
    float tv[16];
    for (int it = 0; it < 10; ++it) {
        float mx = -1e30f;
#pragma unroll
        for (int k = 0; k < 16; ++k) {
            float v = mat[r][s + 4 * k] + gL[s + 4 * k];
            tv[k] = v; mx = fmaxf(mx, v);
        }
        mx = fmaxf(mx, __shfl_xor(mx, 1));
        mx = fmaxf(mx, __shfl_xor(mx, 2));
        float sum = 0.f;
#pragma unroll
        for (int k = 0; k < 16; ++k) sum += __expf(tv[k] - mx);
        sum += __shfl_xor(sum, 1);
        sum += __shfl_xor(sum, 2);
        if (s == 0) fL[r] = -(mx + __logf(sum));
        __syncthreads();
        mx = -1e30f;
#pragma unroll
        for (int k = 0; k < 16; ++k) {
            float v = mat[s + 4 * k][r] + fL[s + 4 * k];
            tv[k] = v; mx = fmaxf(mx, v);
        }
        mx = fmaxf(mx, __shfl_xor(mx, 1));
        mx = fmaxf(mx, __shfl_xor(mx, 2));
        sum = 0.f;
#pragma unroll
        for (int k = 0; k < 16; ++k) sum += __expf(tv[k] - mx);
        sum += __shfl_xor(sum, 1);
        sum += __shfl_xor(sum, 2);
        if (s == 0) gL[r] = -(mx + __logf(sum));
        __syncthreads();
    }
    const float fr = fL[r];
#pragma unroll
    for (int k = 0; k < 16; ++k) {
        int q = s + 4 * k;
        mat[r][q] = __expf(mat[r][q] + fr + gL[q]);
    }
    __syncthreads();
}

template <int C, bool LASTP>
__device__ void layer_body(int bid, int t, SmemLayer& L,
    const int* __restrict__ off1, const int* __restrict__ lst1,
    const int* __restrict__ off2, const int* __restrict__ lst2,
    const int* __restrict__ d1, const int* __restrict__ d2,
    const int* __restrict__ rep1g, const int* __restrict__ rep2g,
    const int* __restrict__ coff1, const int* __restrict__ coff2,
    const int* __restrict__ clst1, const int* __restrict__ clst2,
    const float* __restrict__ Ke, const float* __restrict__ x,
    const float* __restrict__ Kp, int* __restrict__ degcnt,
    const float* __restrict__ W, const float* __restrict__ bb,
    const float* __restrict__ S, const float* __restrict__ c0,
    const float* __restrict__ Wc,
    const float* __restrict__ vprev, float* __restrict__ xn,
    float* __restrict__ vcbuf, float* __restrict__ vout)
{
    // XCD-aware decode: same-batch blocks share bid%8 -> same XCD L2.
    const int b = bid & 7, r2 = bid >> 3;
    for (int k = t; k < C * 16; k += 256) L.WL[k] = W[k];
    if (t < 16) { L.bL[t] = bb[t]; L.SL[t] = S[t]; }
    if (t == 0) L.c0v = c0[0];
    if (LASTP && t < 17) L.WcL[t] = Wc[t];
    const int j0 = off2[b * 65 + r2];
    const int n2 = off2[b * 65 + r2 + 1] - j0;
    for (int k = t; k < n2; k += 256) {
        int j = lst2[b * kE + j0 + k];
        int v = (j << 8) | d2[b * kE + j];
        if (C == 1 && rep2g[b * kE + j] == j) v |= 1 << 16;
        L.jd2[k] = v;
    }
    for (int k = t; k < kE; k += 256) {
        int i = lst1[b * kE + k];
        int v = (i << 8) | d1[b * kE + i];
        if (C == 1 && rep1g[b * kE + i] == i) v |= 1 << 16;
        L.il[k] = v;
    }
    if constexpr (C == 1) {
        for (int k = t; k < kE + 1; k += 256) {
            L.co1L[k] = coff1[b * 193 + k];
            L.co2L[k] = coff2[b * 193 + k];
        }
        for (int k = t; k < kE; k += 256) {
            L.cl1L[k] = (short)clst1[b * kE + k];
            L.cl2L[k] = (short)clst2[b * kE + k];
        }
    }
    if constexpr (C == 17) {
        sink64_local(b, t, L.mat, L.fL, L.gL, vprev);  // includes syncthreads
    } else {
        __syncthreads();
    }

    const int r1 = t >> 2, lane = t & 3;
    const int i0 = off1[b * 65 + r1], i1 = off1[b * 65 + r1 + 1];
    const float* Keb = Ke + (size_t)b * kE * kE;
    const float* KpB = Kp + (size_t)b * kNN;
    int degLocal = 0;

    if constexpr (C == 1) {
        float acc = 0.f;
        for (int k = 0; k < n2; ++k) {
            int pk = L.jd2[k], j = (pk >> 8) & 255, dd2 = pk & 255;
            for (int m = i0 + lane; m < i1; m += 4) {
                int pi = L.il[m], i = (pi >> 8) & 255, dd1 = pi & 255;
                if (dd2 == r2 && dd1 == r1) continue;
                acc += Keb[(size_t)i * kE + j] * KpB[dd1 * 64 + dd2];
            }
        }
        acc += __shfl_xor(acc, 1);
        acc += __shfl_xor(acc, 2);
        if (lane == 0) L.msgT[r1][0] = acc;
        for (int m = i0 + lane; m < i1; m += 4) {
            int pi = L.il[m];
            if (!(pi >> 16)) continue;
            int i = (pi >> 8) & 255, dd1 = pi & 255;
            for (int k = 0; k < n2; ++k) {
                int pk = L.jd2[k];
                if (!(pk >> 16)) continue;
                int j = (pk >> 8) & 255, dd2 = pk & 255;
                float sum = 0.f;
                for (int mm = L.co1L[i]; mm < L.co1L[i + 1]; ++mm) {
                    const float* kr = Keb + (size_t)L.cl1L[mm] * kE;
                    for (int nn = L.co2L[j]; nn < L.co2L[j + 1]; ++nn)
                        sum += kr[L.cl2L[nn]];
                }
                if ((r2 * 64 + r1) != (dd2 * 64 + dd1) && sum > 0.0f) ++degLocal;
            }
        }
        degLocal += __shfl_xor(degLocal, 1);
        degLocal += __shfl_xor(degLocal, 2);
    } else {
        const float* xb = x + (size_t)b * kNN * kXS;
        float acc[5];
#pragma unroll
        for (int cc = 0; cc < 5; ++cc) acc[cc] = 0.f;
        for (int k = 0; k < n2; ++k) {
            int pk = L.jd2[k], j = (pk >> 8) & 255, dd2 = pk & 255;
            const float* xrow = xb + (size_t)(dd2 * 64) * kXS;
            for (int m = i0; m < i1; ++m) {
                int pi = L.il[m], dd1 = pi & 255;
                if (dd2 == r2 && dd1 == r1) continue;
                int i = (pi >> 8) & 255;
                float kv = Keb[(size_t)i * kE + j];
                float4 xv = *(const float4*)(xrow + dd1 * kXS + lane * 4);
                acc[0] += kv * xv.x;
                acc[1] += kv * xv.y;
                acc[2] += kv * xv.z;
                acc[3] += kv * xv.w;
                if (lane == 0) acc[4] += kv * L.mat[dd1][dd2];   // ss from LDS
            }
        }
#pragma unroll
        for (int q = 0; q < 4; ++q)
            L.msgT[r1][lane * 4 + q] = acc[q];
        if (lane == 0) L.msgT[r1][16] = acc[4];
    }
    __syncthreads();

    const int row = r2 * 64 + r1;
    const int idx = b * kNN + row;
    const float kd = KpB[r1 * 64 + r2];
    int degv;
    if constexpr (C == 1) {
        degv = degLocal;
        if (lane == 0) degcnt[idx] = degLocal;
    } else {
        degv = degcnt[idx];
    }
    const float dg = fmaxf((float)(degv + (kd > 0.f ? 1 : 0)), 1.f);
    float m[C];
    if constexpr (C == 1) {
        m[0] = (L.msgT[r1][0] + kd * kd) / dg;
    } else {
        float4 xa  = *(const float4*)(x + (size_t)idx * kXS + 0);
        float4 xb4 = *(const float4*)(x + (size_t)idx * kXS + 4);
        float4 xc4 = *(const float4*)(x + (size_t)idx * kXS + 8);
        float4 xd4 = *(const float4*)(x + (size_t)idx * kXS + 12);
        m[0]  = (L.msgT[r1][0]  + kd * xa.x) / dg;
        m[1]  = (L.msgT[r1][1]  + kd * xa.y) / dg;
        m[2]  = (L.msgT[r1][2]  + kd * xa.z) / dg;
        m[3]  = (L.msgT[r1][3]  + kd * xa.w) / dg;
        m[4]  = (L.msgT[r1][4]  + kd * xb4.x) / dg;
        m[5]  = (L.msgT[r1][5]  + kd * xb4.y) / dg;
        m[6]  = (L.msgT[r1][6]  + kd * xb4.z) / dg;
        m[7]  = (L.msgT[r1][7]  + kd * xb4.w) / dg;
        m[8]  = (L.msgT[r1][8]  + kd * xc4.x) / dg;
        m[9]  = (L.msgT[r1][9]  + kd * xc4.y) / dg;
        m[10] = (L.msgT[r1][10] + kd * xc4.z) / dg;
        m[11] = (L.msgT[r1][11] + kd * xc4.w) / dg;
        m[12] = (L.msgT[r1][12] + kd * xd4.x) / dg;
        m[13] = (L.msgT[r1][13] + kd * xd4.y) / dg;
        m[14] = (L.msgT[r1][14] + kd * xd4.z) / dg;
        m[15] = (L.msgT[r1][15] + kd * xd4.w) / dg;
        m[16] = (L.msgT[r1][16] + kd * L.mat[r1][r2]) / dg;   // own ss via LDS
    }
    float h[4];
    float vpart = 0.f;
#pragma unroll
    for (int ff = 0; ff < 4; ++ff) {
        int f = lane * 4 + ff;
        float a = L.bL[f];
#pragma unroll
        for (int c = 0; c < C; ++c) a += m[c] * L.WL[c * 16 + f];
        h[ff] = fmaxf(a, 0.f);
        vpart += h[ff] * L.SL[f];
    }
    if constexpr (!LASTP) {
        float4 hv; hv.x = h[0]; hv.y = h[1]; hv.z = h[2]; hv.w = h[3];
        *(float4*)(xn + (size_t)idx * kXS + lane * 4) = hv;
    } else {
        float vcp = h[0] * L.WcL[lane * 4 + 0] + h[1] * L.WcL[lane * 4 + 1]
                  + h[2] * L.WcL[lane * 4 + 2] + h[3] * L.WcL[lane * 4 + 3];
        vcp += __shfl_xor(vcp, 1);
        vcp += __shfl_xor(vcp, 2);
        if (lane == 0) vcbuf[idx] = vcp;
    }
    vpart += __shfl_xor(vpart, 1);
    vpart += __shfl_xor(vpart, 2);
    if (lane == 0) vout[idx] = vpart + L.c0v;
}

__global__ __launch_bounds__(256) void k_l0(
    const int* __restrict__ off1, const int* __restrict__ lst1,
    const int* __restrict__ off2, const int* __restrict__ lst2,
    const int* __restrict__ dst1, const int* __restrict__ dst2,
    const int* __restrict__ rep1g, const int* __restrict__ rep2g,
    const int* __restrict__ coff1, const int* __restrict__ coff2,
    const int* __restrict__ clst1, const int* __restrict__ clst2,
    const float* __restrict__ Ke, const float* __restrict__ Kp,
    int* __restrict__ degcnt,
    const float* __restrict__ W0, const float* __restrict__ b0,
    const float* __restrict__ S0, const float* __restrict__ c0,
    float* __restrict__ xA, float* __restrict__ vA)
{
    __shared__ SmemLayer L;
    layer_body<1, false>(blockIdx.x, threadIdx.x, L,
        off1, lst1, off2, lst2, dst1, dst2, rep1g, rep2g,
        coff1, coff2, clst1, clst2, Ke, nullptr, Kp, degcnt,
        W0, b0, S0, c0, nullptr, nullptr, xA, nullptr, vA);
}

__global__ __launch_bounds__(256) void k_l1(
    const int* __restrict__ off1, const int* __restrict__ lst1,
    const int* __restrict__ off2, const int* __restrict__ lst2,
    const int* __restrict__ dst1, const int* __restrict__ dst2,
    const float* __restrict__ Ke, const float* __restrict__ Kp,
    int* __restrict__ degcnt,
    const float* __restrict__ W1, const float* __restrict__ b1,
    const float* __restrict__ S1, const float* __restrict__ c1,
    const float* __restrict__ xA, const float* __restrict__ vA,
    float* __restrict__ xB, float* __restrict__ vB)
{
    __shared__ SmemLayer L;
    layer_body<17, false>(blockIdx.x, threadIdx.x, L,
        off1, lst1, off2, lst2, dst1, dst2, nullptr, nullptr,
        nullptr, nullptr, nullptr, nullptr, Ke, xA, Kp, degcnt,
        W1, b1, S1, c1, nullptr, vA, xB, nullptr, vB);
}

__global__ __launch_bounds__(256) void k_l2(
    const int* __restrict__ off1, const int* __restrict__ lst1,
    const int* __restrict__ off2, const int* __restrict__ lst2,
    const int* __restrict__ dst1, const int* __restrict__ dst2,
    const float* __restrict__ Ke, const float* __restrict__ Kp,
    int* __restrict__ degcnt,
    const float* __restrict__ W2, const float* __restrict__ b2,
    const float* __restrict__ S2, const float* __restrict__ c2,
    const float* __restrict__ Wc,
    const float* __restrict__ xB, const float* __restrict__ vB,
    float* __restrict__ vcbuf, float* __restrict__ vA)
{
    __shared__ SmemLayer L;
    layer_body<17, true>(blockIdx.x, threadIdx.x, L,
        off1, lst1, off2, lst2, dst1, dst2, nullptr, nullptr,
        nullptr, nullptr, nullptr, nullptr, Ke, xB, Kp, degcnt,
        W2, b2, S2, c2, Wc, vB, nullptr, vcbuf, vA);
}

// ===========================================================================
// K4: final — 8 blocks x 576 threads, fully static per-lane arrays (R11).
// ===========================================================================
struct __align__(16) SmemSinkF {
    float mat[65][68]; float fL[72], gL[72];
    float wred[9];
};

__global__ __launch_bounds__(576) void k_final(
    const float* __restrict__ vA, const float* __restrict__ vcbuf,
    const float* __restrict__ Wc, const float* __restrict__ bc,
    const float* __restrict__ binv,
    int* __restrict__ bars, float* __restrict__ out)
{
    const int b = blockIdx.x, t = threadIdx.x;
    __shared__ SmemSinkF S;

    for (int i = t; i < kNN; i += 576) {
        int q = i >> 6, p = i & 63;
        S.mat[p][q] = vA[b * kNN + i] * kTauInv;
    }
    if (t < 72) { S.fL[t] = 0.f; S.gL[t] = 0.f; }
    __syncthreads();

    const int r = t >> 3, s = t & 7;

    // ---- sink64: 8 lanes/row, fully static ----
    {
        const bool act = r < 64;
        const int rr = act ? r : 0;
        float Lr[8], Lc[8], tv[8];
#pragma unroll
        for (int k = 0; k < 8; ++k) {
            Lr[k] = S.mat[rr][s + 8 * k];
            Lc[k] = S.mat[s + 8 * k][rr];
        }
        __syncthreads();
        for (int it = 0; it < 10; ++it) {
            float mx = -1e30f;
#pragma unroll
            for (int k = 0; k < 8; ++k) { tv[k] = Lr[k] + S.gL[s + 8 * k]; mx = fmaxf(mx, tv[k]); }
            mx = fmaxf(mx, __shfl_xor(mx, 1));
            mx = fmaxf(mx, __shfl_xor(mx, 2));
            mx = fmaxf(mx, __shfl_xor(mx, 4));
            float sum = 0.f;
#pragma unroll
            for (int k = 0; k < 8; ++k) sum += __expf(tv[k] - mx);
            sum += __shfl_xor(sum, 1);
            sum += __shfl_xor(sum, 2);
            sum += __shfl_xor(sum, 4);
            if (act && s == 0) S.fL[r] = -(mx + __logf(sum));
            __syncthreads();
            mx = -1e30f;
#pragma unroll
            for (int k = 0; k < 8; ++k) { tv[k] = Lc[k] + S.fL[s + 8 * k]; mx = fmaxf(mx, tv[k]); }
            mx = fmaxf(mx, __shfl_xor(mx, 1));
            mx = fmaxf(mx, __shfl_xor(mx, 2));
            mx = fmaxf(mx, __shfl_xor(mx, 4));
            sum = 0.f;
#pragma unroll
            for (int k = 0; k < 8; ++k) sum += __expf(tv[k] - mx);
            sum += __shfl_xor(sum, 1);
            sum += __shfl_xor(sum, 2);
            sum += __shfl_xor(sum, 4);
            if (act && s == 0) S.gL[r] = -(mx + __logf(sum));
            __syncthreads();
        }
        if (act) {
            const float fr = S.fL[r];
#pragma unroll
            for (int k = 0; k < 8; ++k) {
                int q = s + 8 * k;
                S.mat[r][q] = __expf(Lr[k] + fr + S.gL[q]);   // ss prob
            }
        }
    }
    __syncthreads();

    // ---- build 65x65 log matrix in place ----
    {
        const float Wc16 = Wc[16], bcv = bc[0], binvv = binv[0];
        const float* vcb = vcbuf + (size_t)b * kNN;
        for (int idx = t; idx < 65 * 65; idx += 576) {
            int q = idx / 65, p = idx - q * 65;
            float v;
            if (p < 64 && q < 64)
                v = vcb[q * 64 + p] + S.mat[p][q] * Wc16 + bcv;
            else v = binvv;
            S.mat[p][q] = v;
        }
        if (t < 72) { S.fL[t] = 0.f; S.gL[t] = 0.f; }
    }
    __syncthreads();

    // ---- sink65: 8 lanes/row, 9th element static-guarded ----
    const bool act = r < 65;
    const int rr = act ? r : 0;
    float Lrow[9], Lcol[9], tv[9];
#pragma unroll
    for (int k = 0; k < 8; ++k) {
        Lrow[k] = S.mat[rr][s + 8 * k];
        Lcol[k] = S.mat[s + 8 * k][rr];
    }
    Lrow[8] = (s == 0) ? S.mat[rr][64] : -1e30f;
    Lcol[8] = (s == 0) ? S.mat[64][rr] : -1e30f;
    __syncthreads();

    for (int it = 0; it < 10; ++it) {
        float mx = -1e30f;
#pragma unroll
        for (int k = 0; k < 9; ++k) { tv[k] = Lrow[k] + S.gL[s + 8 * k]; mx = fmaxf(mx, tv[k]); }
        mx = fmaxf(mx, __shfl_xor(mx, 1));
        mx = fmaxf(mx, __shfl_xor(mx, 2));
        mx = fmaxf(mx, __shfl_xor(mx, 4));
        float sum = 0.f;
#pragma unroll
        for (int k = 0; k < 9; ++k) sum += __expf(tv[k] - mx);
        sum += __shfl_xor(sum, 1);
        sum += __shfl_xor(sum, 2);
        sum += __shfl_xor(sum, 4);
        if (act && s == 0) S.fL[r] = -(mx + __logf(sum));
        __syncthreads();
        mx = -1e30f;
#pragma unroll
        for (int k = 0; k < 9; ++k) { tv[k] = Lcol[k] + S.fL[s + 8 * k]; mx = fmaxf(mx, tv[k]); }
        mx = fmaxf(mx, __shfl_xor(mx, 1));
        mx = fmaxf(mx, __shfl_xor(mx, 2));
        mx = fmaxf(mx, __shfl_xor(mx, 4));
        sum = 0.f;
#pragma unroll
        for (int k = 0; k < 9; ++k) sum += __expf(tv[k] - mx);
        sum += __shfl_xor(sum, 1);
        sum += __shfl_xor(sum, 2);
        sum += __shfl_xor(sum, 4);
        if (act && s == 0) S.gL[r] = -(mx + __logf(sum));
        __syncthreads();
    }

    float ev[8];
    float lmax = 0.f;
    if (r < 64) {
        const float fr = S.fL[r];
#pragma unroll
        for (int k = 0; k < 8; ++k) {
            ev[k] = __expf(Lrow[k] + fr + S.gL[s + 8 * k]);
            lmax = fmaxf(lmax, ev[k]);
        }
    }
#pragma unroll
    for (int o = 32; o >= 1; o >>= 1) lmax = fmaxf(lmax, __shfl_xor(lmax, o));
    if ((t & 63) == 0) S.wred[t >> 6] = lmax;
    __syncthreads();
    int* mcnt = bars + 3584;
    int* gmax = bars + 3600;
    if (t == 0) {
        float mb = S.wred[0];
#pragma unroll
        for (int w = 1; w < 9; ++w) mb = fmaxf(mb, S.wred[w]);
        atomicMax(gmax, __float_as_int(mb));   // all values > 0
        asm volatile("s_waitcnt vmcnt(0)" ::: "memory");
        __hip_atomic_fetch_add(mcnt, 1, __ATOMIC_RELAXED, __HIP_MEMORY_SCOPE_AGENT);
        while (__hip_atomic_load(mcnt, __ATOMIC_RELAXED, __HIP_MEMORY_SCOPE_AGENT) < 8)
            __builtin_amdgcn_s_sleep(2);
    }
    __syncthreads();
    const float inv = 1.f / __int_as_float(
        __hip_atomic_load(gmax, __ATOMIC_RELAXED, __HIP_MEMORY_SCOPE_AGENT));
    if (r < 64) {
#pragma unroll
        for (int k = 0; k < 8; ++k)
            out[((size_t)b * kN + r) * kN + s + 8 * k] = ev[k] * inv;
    }
}

// ---------------------------------------------------------------------------
extern "C" void kernel_launch(void* const* d_in, const int* in_sizes, int n_in,
                              void* d_out, int out_size, void* d_ws, size_t ws_size,
                              hipStream_t stream)
{
    (void)in_sizes; (void)n_in; (void)out_size; (void)ws_size;

    const float* x1    = (const float*)d_in[0];
    const float* x2    = (const float*)d_in[1];
    const float* e1    = (const float*)d_in[2];
    const float* e2    = (const float*)d_in[3];
    const float* Wp    = (const float*)d_in[4];
    const float* bp    = (const float*)d_in[5];
    const float* gamma = (const float*)d_in[6];
    const float* beta  = (const float*)d_in[7];
    const float* W0 = (const float*)d_in[8];
    const float* b0 = (const float*)d_in[9];
    const float* S0 = (const float*)d_in[10];
    const float* c0 = (const float*)d_in[11];
    const float* W1 = (const float*)d_in[12];
    const float* b1 = (const float*)d_in[13];
    const float* S1 = (const float*)d_in[14];
    const float* c1 = (const float*)d_in[15];
    const float* W2 = (const float*)d_in[16];
    const float* b2 = (const float*)d_in[17];
    const float* S2 = (const float*)d_in[18];
    const float* c2 = (const float*)d_in[19];
    const float* Wc = (const float*)d_in[20];
    const float* bc = (const float*)d_in[21];
    const float* binv = (const float*)d_in[22];
    const int* src1 = (const int*)d_in[23];
    const int* dst1 = (const int*)d_in[24];
    const int* src2 = (const int*)d_in[25];
    const int* dst2 = (const int*)d_in[26];

    float* out = (float*)d_out;
    float* wsf = (float*)d_ws;

    float* hbuf  = wsf;                    // 1,048,576
    float* P     = hbuf + 1048576;         // 4,194,304 (4 x 4MB z-slices)
    float* Kp    = P + 4194304;            // 32,768
    float* Ke    = Kp + 32768;             // 294,912
    float* vA    = Ke + 294912;            // 32,768
    float* vB    = vA + 32768;             // 32,768
    float* xA    = vB + 32768;             // 524,288 (stride 16)
    float* xB    = xA + 524288;            // 524,288
    float* vcbuf = xB + 524288;            // 32,768
    int*   degcnt = (int*)(vcbuf + 32768); // 32,768
    int*   off1 = degcnt + 32768;          // 520
    int*   off2 = off1 + 520;              // 520
    int*   lst1 = off2 + 520;              // 1,536
    int*   lst2 = lst1 + 1536;             // 1,536
    int*   rep1g = lst2 + 1536;            // 1,536
    int*   rep2g = rep1g + 1536;           // 1,536
    int*   coff1 = rep2g + 1536;           // 1,544
    int*   coff2 = coff1 + 1544;           // 1,544
    int*   clst1 = coff2 + 1544;           // 1,536
    int*   clst2 = clst1 + 1536;           // 1,536
    float* stats = (float*)(clst2 + 1536); // 2,048 (zeroed by k_projcsr)
    int*   bars  = (int*)(stats + 2048);   // 4,096 (2 words zeroed by k_sim)

    k_projcsr<<<dim3(1032), dim3(256), 0, stream>>>(
        x1, x2, e1, e2, Wp, src1, dst1, src2, dst2, P, stats,
        off1, off2, lst1, lst2, rep1g, rep2g, coff1, coff2, clst1, clst2);
    k_reduce<<<dim3(256), dim3(256), 0, stream>>>(P, bp, hbuf, stats);
    k_sim<<<dim3(320), dim3(256), 0, stream>>>(hbuf, stats, gamma, beta, Kp, Ke, bars);
    k_l0<<<dim3(512), dim3(256), 0, stream>>>(
        off1, lst1, off2, lst2, dst1, dst2, rep1g, rep2g,
        coff1, coff2, clst1, clst2, Ke, Kp, degcnt,
        W0, b0, S0, c0, xA, vA);
    k_l1<<<dim3(512), dim3(256), 0, stream>>>(
        off1, lst1, off2, lst2, dst1, dst2, Ke, Kp, degcnt,
        W1, b1, S1, c1, xA, vA, xB, vB);
    k_l2<<<dim3(512), dim3(256), 0, stream>>>(
        off1, lst1, off2, lst2, dst1, dst2, Ke, Kp, degcnt,
        W2, b2, S2, c2, Wc, xB, vB, vcbuf, vA);
    k_final<<<dim3(8), dim3(576), 0, stream>>>(vA, vcbuf, Wc, bc, binv, bars, out);
}